// Round 4
// baseline (721.579 us; speedup 1.0000x reference)
//
#include <hip/hip_runtime.h>
#include <hip/hip_bf16.h>

#define HID 4096
#define EQKV 6144
#define NH 32
#define NKV 8
#define GQ 4
#define D 128
#define WIN 2048

// ---------------- GEMM: out[b][e] = sum_h X[b][h] * W[h][e] ----------------
// X: [32][4096] fp32.  W: [4096][E] fp32.  Block owns 32 e's for ALL 32 b.
// 256 threads: e_local = t&31, b-group = t>>5 (4 b's each). x staged in LDS.
template<int E>
__global__ __launch_bounds__(256) void k_gemm(const float* __restrict__ X,
                                              const float* __restrict__ W,
                                              float* __restrict__ out) {
    __shared__ float xs[32][68];
    const int t = threadIdx.x;
    const int el = t & 31, bg = t >> 5;
    const int e = blockIdx.x * 32 + el;
    float acc[4] = {0.f, 0.f, 0.f, 0.f};

    for (int h0 = 0; h0 < HID; h0 += 64) {
        __syncthreads();
        {   // stage x[0..32)[h0..h0+64): thread loads 8 floats of one b-row
            const int bs = t >> 3, hs = (t & 7) * 8;
            const float4 v0 = *(const float4*)&X[(size_t)bs * HID + h0 + hs];
            const float4 v1 = *(const float4*)&X[(size_t)bs * HID + h0 + hs + 4];
            *(float4*)&xs[bs][hs]     = v0;
            *(float4*)&xs[bs][hs + 4] = v1;
        }
        __syncthreads();
#pragma unroll 4
        for (int hh = 0; hh < 64; hh += 4) {
            const float w0 = W[(size_t)(h0 + hh + 0) * E + e];
            const float w1 = W[(size_t)(h0 + hh + 1) * E + e];
            const float w2 = W[(size_t)(h0 + hh + 2) * E + e];
            const float w3 = W[(size_t)(h0 + hh + 3) * E + e];
#pragma unroll
            for (int j = 0; j < 4; ++j) {
                const float4 xv = *(const float4*)&xs[bg * 4 + j][hh];
                acc[j] = fmaf(xv.x, w0,
                         fmaf(xv.y, w1,
                         fmaf(xv.z, w2,
                         fmaf(xv.w, w3, acc[j]))));
            }
        }
    }
#pragma unroll
    for (int j = 0; j < 4; ++j) {
        const int b = bg * 4 + j;
        out[(size_t)b * E + e] = acc[j];
    }
}

// ---------------- rope: dense DxD rotation of q and k ----------------
__global__ void k_rope(const float* __restrict__ xqkv, const float* __restrict__ R,
                       float* __restrict__ q_rot, float* __restrict__ k_rot) {
    const int bid = blockIdx.x;             // 0 .. 32*(NH+NKV)-1
    const int b = bid / (NH + NKV);
    const int hd = bid % (NH + NKV);
    const float* src; float* dst;
    if (hd < NH) {
        src = xqkv + (size_t)b * EQKV + hd * D;
        dst = q_rot + ((size_t)b * NH + hd) * D;
    } else {
        const int kv = hd - NH;
        src = xqkv + (size_t)b * EQKV + NH * D + kv * D;
        dst = k_rot + ((size_t)b * NKV + kv) * D;
    }
    const int e = threadIdx.x;
    float acc = 0.f;
    for (int d = 0; d < D; ++d) acc = fmaf(src[d], R[(size_t)d * D + e], acc);
    dst[e] = acc;
}

// ---------------- attention: one block per (b, kv), 512 threads ----------------
__global__ __launch_bounds__(512) void k_attn(
        const float* __restrict__ q_rot, const float* __restrict__ k_rot,
        const float* __restrict__ xqkv,
        const float* __restrict__ cache_k, const float* __restrict__ cache_v,
        const int* __restrict__ p_start, const int* __restrict__ p_cur,
        float* __restrict__ attn_out) {
    __shared__ float qs[4 * D];
    __shared__ float kn[D];
    __shared__ float vn[D];
    __shared__ float S[4 * WIN];
    __shared__ float recip[4];
    __shared__ float red[8 * 4 * D];

    const int t = threadIdx.x;
    const int bkv = blockIdx.x;
    const int b = bkv >> 3, kv = bkv & 7;
    const int l = t & 63, w = t >> 6;
    const int ls = min(p_start[0] + 1, WIN);
    const int cur = p_cur[0];

    {   // stage q (4 heads), new k, new v
        const int g = t >> 7, d = t & 127;
        qs[g * D + d] = q_rot[(((size_t)b * NH) + kv * GQ + g) * D + d];
        if (t < 128) kn[t] = k_rot[((size_t)b * NKV + kv) * D + t];
        else if (t < 256) {
            const int d2 = t - 128;
            vn[d2] = xqkv[(size_t)b * EQKV + (NH + NKV) * D + kv * D + d2];
        }
    }
    __syncthreads();

    const float scale = 0.08838834764831845f;   // 1/sqrt(128)
    const size_t base = (size_t)bkv * WIN * D;

    // ---- pass 1: scores. 16 lanes per row p, each lane 8 d's. ----
    {
        const int sub = l & 15, r = l >> 4;
        const int d0 = sub * 8;
        float qreg[4][8];
#pragma unroll
        for (int g = 0; g < 4; ++g)
#pragma unroll
            for (int j = 0; j < 8; ++j) qreg[g][j] = qs[g * D + d0 + j];
        for (int it = 0; it < WIN / 32; ++it) {
            const int p = it * 32 + w * 4 + r;
            if (p < ls) {
                const float4 a = *(const float4*)(cache_k + base + (size_t)p * D + d0);
                const float4 c = *(const float4*)(cache_k + base + (size_t)p * D + d0 + 4);
                const float kk[8] = {a.x, a.y, a.z, a.w, c.x, c.y, c.z, c.w};
                float s4[4] = {0.f, 0.f, 0.f, 0.f};
#pragma unroll
                for (int g = 0; g < 4; ++g)
#pragma unroll
                    for (int j = 0; j < 8; ++j) s4[g] = fmaf(qreg[g][j], kk[j], s4[g]);
#pragma unroll
                for (int off = 1; off < 16; off <<= 1)
#pragma unroll
                    for (int g = 0; g < 4; ++g) s4[g] += __shfl_xor(s4[g], off, 16);
                if (sub == 0) {
                    S[0 * WIN + p] = s4[0] * scale;
                    S[1 * WIN + p] = s4[1] * scale;
                    S[2 * WIN + p] = s4[2] * scale;
                    S[3 * WIN + p] = s4[3] * scale;
                }
            }
        }
    }
    __syncthreads();

    // ---- patch position cur with the NEW k (reference overwrites cache) ----
    if (cur < ls && t < 4) {
        float a = 0.f;
        for (int d = 0; d < D; ++d) a = fmaf(qs[t * D + d], kn[d], a);
        S[t * WIN + cur] = a * scale;
    }
    __syncthreads();

    // ---- softmax (waves 0..3, one per g) ----
    if (w < 4) {
        float m = -1e30f;
        for (int p = l; p < ls; p += 64) m = fmaxf(m, S[w * WIN + p]);
#pragma unroll
        for (int off = 32; off; off >>= 1) m = fmaxf(m, __shfl_xor(m, off, 64));
        float sum = 0.f;
        for (int p = l; p < ls; p += 64) {
            const float e = __expf(S[w * WIN + p] - m);
            S[w * WIN + p] = e;
            sum += e;
        }
#pragma unroll
        for (int off = 32; off; off >>= 1) sum += __shfl_xor(sum, off, 64);
        if (l == 0) recip[w] = 1.f / sum;
    }
    __syncthreads();

    // ---- pass 2: PV. thread owns 8 d's, strides p by 32. ----
    {
        const int s = t & 15, pt = t >> 4;      // pt = w*4 + (l>>4)
        const int d0 = s * 8;
        float vn8[8];
#pragma unroll
        for (int j = 0; j < 8; ++j) vn8[j] = vn[d0 + j];
        float acc[4][8];
#pragma unroll
        for (int g = 0; g < 4; ++g)
#pragma unroll
            for (int j = 0; j < 8; ++j) acc[g][j] = 0.f;
        for (int i = 0; i < WIN / 32; ++i) {
            const int p = i * 32 + pt;
            if (p < ls) {
                const float4 a = *(const float4*)(cache_v + base + (size_t)p * D + d0);
                const float4 c = *(const float4*)(cache_v + base + (size_t)p * D + d0 + 4);
                float vv[8] = {a.x, a.y, a.z, a.w, c.x, c.y, c.z, c.w};
                if (p == cur) {
#pragma unroll
                    for (int j = 0; j < 8; ++j) vv[j] = vn8[j];
                }
                const float s0 = S[0 * WIN + p], s1 = S[1 * WIN + p];
                const float s2 = S[2 * WIN + p], s3 = S[3 * WIN + p];
#pragma unroll
                for (int j = 0; j < 8; ++j) {
                    acc[0][j] = fmaf(s0, vv[j], acc[0][j]);
                    acc[1][j] = fmaf(s1, vv[j], acc[1][j]);
                    acc[2][j] = fmaf(s2, vv[j], acc[2][j]);
                    acc[3][j] = fmaf(s3, vv[j], acc[3][j]);
                }
            }
        }
        // reduce over the 4 in-wave p-groups (lane bits 4,5)
#pragma unroll
        for (int off = 16; off <= 32; off <<= 1)
#pragma unroll
            for (int g = 0; g < 4; ++g)
#pragma unroll
                for (int j = 0; j < 8; ++j)
                    acc[g][j] += __shfl_xor(acc[g][j], off, 64);
        if (l < 16) {
#pragma unroll
            for (int g = 0; g < 4; ++g)
#pragma unroll
                for (int j = 0; j < 8; ++j)
                    red[(w * 4 + g) * D + l * 8 + j] = acc[g][j];
        }
    }
    __syncthreads();

    {   // cross-wave reduce + write attn_out[b][h] (natural layout for GEMM2)
        const int g = t >> 7, d = t & 127;
        float sum = 0.f;
#pragma unroll
        for (int w8 = 0; w8 < 8; ++w8) sum += red[(w8 * 4 + g) * D + d];
        sum *= recip[g];
        attn_out[(size_t)b * HID + (kv * GQ + g) * D + d] = sum;
    }
}

// ---------------- host launch ----------------
extern "C" void kernel_launch(void* const* d_in, const int* in_sizes, int n_in,
                              void* d_out, int out_size, void* d_ws, size_t ws_size,
                              hipStream_t stream) {
    const float* x    = (const float*)d_in[0];
    const float* wqkv = (const float*)d_in[1];
    const float* wo   = (const float*)d_in[2];
    const float* rot  = (const float*)d_in[3];
    const float* ck   = (const float*)d_in[4];
    const float* cv   = (const float*)d_in[5];
    const int*   sp   = (const int*)d_in[6];
    const int*   cp   = (const int*)d_in[7];

    float* ws     = (float*)d_ws;
    float* xqkv_o = ws;                 // 32*6144   = 196608
    float* q_rot  = ws + 196608;        // 32*32*128 = 131072
    float* k_rot  = ws + 327680;        // 32*8*128  = 32768
    float* attn_o = ws + 360448;        // 32*4096   = 131072
    // total: 491520 floats = 1.97 MB

    k_gemm<EQKV><<<EQKV / 32, 256, 0, stream>>>(x, wqkv, xqkv_o);
    k_rope<<<32 * (NH + NKV), 128, 0, stream>>>(xqkv_o, rot, q_rot, k_rot);
    k_attn<<<256, 512, 0, stream>>>(q_rot, k_rot, xqkv_o, ck, cv, sp, cp, attn_o);
    k_gemm<HID><<<HID / 32, 256, 0, stream>>>(attn_o, wo, (float*)d_out);
}

// Round 5
// 205.950 us; speedup vs baseline: 3.5037x; 3.5037x over previous
//
#include <hip/hip_runtime.h>
#include <hip/hip_bf16.h>

#define HID 4096
#define EQKV 6144
#define NH 32
#define NKV 8
#define GQ 4
#define D 128
#define WIN 2048
#define NCH 16   // K-chunks (4096 / 256)

// ------- split-K GEMM: part[chunk][b][e] = sum_{h in chunk} X[b][h] * W[h][e]
// grid (E/128, NCH). block 256 = 4 waves; wave owns 64 h of the 256-h chunk;
// lane owns 2 e. X chunk staged in LDS h-major; W streamed coalesced float2.
template<int E>
__global__ __launch_bounds__(256) void k_gemm_split(const float* __restrict__ X,
                                                    const float* __restrict__ W,
                                                    float* __restrict__ part) {
    __shared__ float xs[256][36];          // [h_local][b], pad 36 keeps float4 align
    __shared__ float2 red[8][64][4];
    const int t = threadIdx.x;
    const int wv = t >> 6, ln = t & 63;
    const int e = blockIdx.x * 128 + ln * 2;
    const int h0 = blockIdx.y * 256;

    {   // stage X[0..32)[h0..h0+256) -> xs[hl][b]
        const int bs = t >> 3, hs = (t & 7) * 32;
#pragma unroll
        for (int i = 0; i < 8; ++i) {
            const float4 v = *(const float4*)&X[(size_t)bs * HID + h0 + hs + i * 4];
            xs[hs + i * 4 + 0][bs] = v.x;
            xs[hs + i * 4 + 1][bs] = v.y;
            xs[hs + i * 4 + 2][bs] = v.z;
            xs[hs + i * 4 + 3][bs] = v.w;
        }
    }
    __syncthreads();

    float2 acc[32];
#pragma unroll
    for (int i = 0; i < 32; ++i) acc[i] = make_float2(0.f, 0.f);

    const float* Wp = W + (size_t)(h0 + wv * 64) * E + e;
    const int hl0 = wv * 64;
    for (int hh = 0; hh < 64; ++hh) {
        const float2 w2 = *(const float2*)Wp;
        Wp += E;
#pragma unroll
        for (int i = 0; i < 8; ++i) {
            const float4 xv = *(const float4*)&xs[hl0 + hh][i * 4];
            acc[i * 4 + 0].x = fmaf(xv.x, w2.x, acc[i * 4 + 0].x);
            acc[i * 4 + 0].y = fmaf(xv.x, w2.y, acc[i * 4 + 0].y);
            acc[i * 4 + 1].x = fmaf(xv.y, w2.x, acc[i * 4 + 1].x);
            acc[i * 4 + 1].y = fmaf(xv.y, w2.y, acc[i * 4 + 1].y);
            acc[i * 4 + 2].x = fmaf(xv.z, w2.x, acc[i * 4 + 2].x);
            acc[i * 4 + 2].y = fmaf(xv.z, w2.y, acc[i * 4 + 2].y);
            acc[i * 4 + 3].x = fmaf(xv.w, w2.x, acc[i * 4 + 3].x);
            acc[i * 4 + 3].y = fmaf(xv.w, w2.y, acc[i * 4 + 3].y);
        }
    }

    // cross-wave reduce: 4 waves cover different h-subs of the same e-tile
    for (int r = 0; r < 4; ++r) {
#pragma unroll
        for (int j = 0; j < 8; ++j) red[j][ln][wv] = acc[r * 8 + j];
        __syncthreads();
#pragma unroll
        for (int it = 0; it < 2; ++it) {
            const int item = t + it * 256;
            const int ln2 = item & 63, j2 = item >> 6;
            const float2 a0 = red[j2][ln2][0], a1 = red[j2][ln2][1];
            const float2 a2 = red[j2][ln2][2], a3 = red[j2][ln2][3];
            const float2 s = make_float2((a0.x + a1.x) + (a2.x + a3.x),
                                         (a0.y + a1.y) + (a2.y + a3.y));
            const int b2 = r * 8 + j2;
            const int e2 = blockIdx.x * 128 + ln2 * 2;
            *(float2*)(part + ((size_t)blockIdx.y * 32 + b2) * E + e2) = s;
        }
        __syncthreads();
    }
}

// ---------------- reduce NCH partial chunks (fp32 out) ----------------
__global__ void k_reduce_f32(const float* __restrict__ part,
                             float* __restrict__ out, const int n) {
    const int i4 = (blockIdx.x * 256 + threadIdx.x) * 4;
    if (i4 >= n) return;
    float4 s = make_float4(0.f, 0.f, 0.f, 0.f);
#pragma unroll
    for (int c = 0; c < NCH; ++c) {
        const float4 p = *(const float4*)(part + (size_t)c * n + i4);
        s.x += p.x; s.y += p.y; s.z += p.z; s.w += p.w;
    }
    *(float4*)(out + i4) = s;
}

// ---------------- rope: dense DxD rotation of q and k ----------------
__global__ void k_rope(const float* __restrict__ xqkv, const float* __restrict__ R,
                       float* __restrict__ q_rot, float* __restrict__ k_rot) {
    const int bid = blockIdx.x;
    const int b = bid / (NH + NKV);
    const int hd = bid % (NH + NKV);
    const float* src; float* dst;
    if (hd < NH) {
        src = xqkv + (size_t)b * EQKV + hd * D;
        dst = q_rot + ((size_t)b * NH + hd) * D;
    } else {
        const int kv = hd - NH;
        src = xqkv + (size_t)b * EQKV + NH * D + kv * D;
        dst = k_rot + ((size_t)b * NKV + kv) * D;
    }
    const int e = threadIdx.x;
    float acc = 0.f;
    for (int d = 0; d < D; ++d) acc = fmaf(src[d], R[(size_t)d * D + e], acc);
    dst[e] = acc;
}

// ---------------- attention: one block per (b, kv), 512 threads ----------------
__global__ __launch_bounds__(512) void k_attn(
        const float* __restrict__ q_rot, const float* __restrict__ k_rot,
        const float* __restrict__ xqkv,
        const float* __restrict__ cache_k, const float* __restrict__ cache_v,
        const int* __restrict__ p_start, const int* __restrict__ p_cur,
        float* __restrict__ attn_out) {
    __shared__ float qs[4 * D];
    __shared__ float kn[D];
    __shared__ float vn[D];
    __shared__ float S[4 * WIN];
    __shared__ float recip[4];
    __shared__ float red[8 * 4 * D];

    const int t = threadIdx.x;
    const int bkv = blockIdx.x;
    const int b = bkv >> 3, kv = bkv & 7;
    const int l = t & 63, w = t >> 6;
    const int ls = min(p_start[0] + 1, WIN);
    const int cur = p_cur[0];

    {   // stage q (4 heads), new k, new v
        const int g = t >> 7, d = t & 127;
        qs[g * D + d] = q_rot[(((size_t)b * NH) + kv * GQ + g) * D + d];
        if (t < 128) kn[t] = k_rot[((size_t)b * NKV + kv) * D + t];
        else if (t < 256) {
            const int d2 = t - 128;
            vn[d2] = xqkv[(size_t)b * EQKV + (NH + NKV) * D + kv * D + d2];
        }
    }
    __syncthreads();

    const float scale = 0.08838834764831845f;   // 1/sqrt(128)
    const size_t base = (size_t)bkv * WIN * D;

    // ---- pass 1: scores. 16 lanes per row p, each lane 8 d's. ----
    {
        const int sub = l & 15, r = l >> 4;
        const int d0 = sub * 8;
        float qreg[4][8];
#pragma unroll
        for (int g = 0; g < 4; ++g)
#pragma unroll
            for (int j = 0; j < 8; ++j) qreg[g][j] = qs[g * D + d0 + j];
        for (int it = 0; it < WIN / 32; ++it) {
            const int p = it * 32 + w * 4 + r;
            if (p < ls) {
                const float4 a = *(const float4*)(cache_k + base + (size_t)p * D + d0);
                const float4 c = *(const float4*)(cache_k + base + (size_t)p * D + d0 + 4);
                const float kk[8] = {a.x, a.y, a.z, a.w, c.x, c.y, c.z, c.w};
                float s4[4] = {0.f, 0.f, 0.f, 0.f};
#pragma unroll
                for (int g = 0; g < 4; ++g)
#pragma unroll
                    for (int j = 0; j < 8; ++j) s4[g] = fmaf(qreg[g][j], kk[j], s4[g]);
#pragma unroll
                for (int off = 1; off < 16; off <<= 1)
#pragma unroll
                    for (int g = 0; g < 4; ++g) s4[g] += __shfl_xor(s4[g], off, 16);
                if (sub == 0) {
                    S[0 * WIN + p] = s4[0] * scale;
                    S[1 * WIN + p] = s4[1] * scale;
                    S[2 * WIN + p] = s4[2] * scale;
                    S[3 * WIN + p] = s4[3] * scale;
                }
            }
        }
    }
    __syncthreads();

    // ---- patch position cur with the NEW k (reference overwrites cache) ----
    if (cur < ls && t < 4) {
        float a = 0.f;
        for (int d = 0; d < D; ++d) a = fmaf(qs[t * D + d], kn[d], a);
        S[t * WIN + cur] = a * scale;
    }
    __syncthreads();

    // ---- softmax (waves 0..3, one per g) ----
    if (w < 4) {
        float m = -1e30f;
        for (int p = l; p < ls; p += 64) m = fmaxf(m, S[w * WIN + p]);
#pragma unroll
        for (int off = 32; off; off >>= 1) m = fmaxf(m, __shfl_xor(m, off, 64));
        float sum = 0.f;
        for (int p = l; p < ls; p += 64) {
            const float e = __expf(S[w * WIN + p] - m);
            S[w * WIN + p] = e;
            sum += e;
        }
#pragma unroll
        for (int off = 32; off; off >>= 1) sum += __shfl_xor(sum, off, 64);
        if (l == 0) recip[w] = 1.f / sum;
    }
    __syncthreads();

    // ---- pass 2: PV. thread owns 8 d's, strides p by 32. ----
    {
        const int s = t & 15, pt = t >> 4;
        const int d0 = s * 8;
        float vn8[8];
#pragma unroll
        for (int j = 0; j < 8; ++j) vn8[j] = vn[d0 + j];
        float acc[4][8];
#pragma unroll
        for (int g = 0; g < 4; ++g)
#pragma unroll
            for (int j = 0; j < 8; ++j) acc[g][j] = 0.f;
        for (int i = 0; i < WIN / 32; ++i) {
            const int p = i * 32 + pt;
            if (p < ls) {
                const float4 a = *(const float4*)(cache_v + base + (size_t)p * D + d0);
                const float4 c = *(const float4*)(cache_v + base + (size_t)p * D + d0 + 4);
                float vv[8] = {a.x, a.y, a.z, a.w, c.x, c.y, c.z, c.w};
                if (p == cur) {
#pragma unroll
                    for (int j = 0; j < 8; ++j) vv[j] = vn8[j];
                }
                const float s0 = S[0 * WIN + p], s1 = S[1 * WIN + p];
                const float s2 = S[2 * WIN + p], s3 = S[3 * WIN + p];
#pragma unroll
                for (int j = 0; j < 8; ++j) {
                    acc[0][j] = fmaf(s0, vv[j], acc[0][j]);
                    acc[1][j] = fmaf(s1, vv[j], acc[1][j]);
                    acc[2][j] = fmaf(s2, vv[j], acc[2][j]);
                    acc[3][j] = fmaf(s3, vv[j], acc[3][j]);
                }
            }
        }
#pragma unroll
        for (int off = 16; off <= 32; off <<= 1)
#pragma unroll
            for (int g = 0; g < 4; ++g)
#pragma unroll
                for (int j = 0; j < 8; ++j)
                    acc[g][j] += __shfl_xor(acc[g][j], off, 64);
        if (l < 16) {
#pragma unroll
            for (int g = 0; g < 4; ++g)
#pragma unroll
                for (int j = 0; j < 8; ++j)
                    red[(w * 4 + g) * D + l * 8 + j] = acc[g][j];
        }
    }
    __syncthreads();

    {   // cross-wave reduce + write attn_out[b][h]
        const int g = t >> 7, d = t & 127;
        float sum = 0.f;
#pragma unroll
        for (int w8 = 0; w8 < 8; ++w8) sum += red[(w8 * 4 + g) * D + d];
        sum *= recip[g];
        attn_out[(size_t)b * HID + (kv * GQ + g) * D + d] = sum;
    }
}

// ---------------- host launch ----------------
extern "C" void kernel_launch(void* const* d_in, const int* in_sizes, int n_in,
                              void* d_out, int out_size, void* d_ws, size_t ws_size,
                              hipStream_t stream) {
    const float* x    = (const float*)d_in[0];
    const float* wqkv = (const float*)d_in[1];
    const float* wo   = (const float*)d_in[2];
    const float* rot  = (const float*)d_in[3];
    const float* ck   = (const float*)d_in[4];
    const float* cv   = (const float*)d_in[5];
    const int*   sp   = (const int*)d_in[6];
    const int*   cp   = (const int*)d_in[7];

    float* ws     = (float*)d_ws;
    float* xqkv_o = ws;                     // 32*6144   = 196608
    float* q_rot  = ws + 196608;            // 32*32*128 = 131072
    float* k_rot  = ws + 327680;            // 32*8*128  = 32768
    float* attn_o = ws + 360448;            // 32*4096   = 131072
    float* part   = ws + 491520;            // NCH*32*6144 = 3145728 (reused)
    // total: 3,637,248 floats = 14.5 MB

    k_gemm_split<EQKV><<<dim3(EQKV / 128, NCH), 256, 0, stream>>>(x, wqkv, part);
    k_reduce_f32<<<192, 256, 0, stream>>>(part, xqkv_o, 32 * EQKV);
    k_rope<<<32 * (NH + NKV), 128, 0, stream>>>(xqkv_o, rot, q_rot, k_rot);
    k_attn<<<256, 512, 0, stream>>>(q_rot, k_rot, xqkv_o, ck, cv, sp, cp, attn_o);
    k_gemm_split<HID><<<dim3(HID / 128, NCH), 256, 0, stream>>>(attn_o, wo, part);
    k_reduce_f32<<<128, 256, 0, stream>>>(part, (float*)d_out, 32 * HID);
}

// Round 6
// 190.958 us; speedup vs baseline: 3.7787x; 1.0785x over previous
//
#include <hip/hip_runtime.h>
#include <hip/hip_bf16.h>

#define HID 4096
#define EQKV 6144
#define NH 32
#define NKV 8
#define GQ 4
#define D 128
#define WIN 2048
#define NCH 16   // K-chunks for split-K GEMM (4096 / 256)
#define NCHK 4   // position chunks for flash-decode attention
#define CLEN (WIN / NCHK)   // 512

// ------- split-K GEMM: part[chunk][b][e] = sum_{h in chunk} X[b][h] * W[h][e]
template<int E>
__global__ __launch_bounds__(256) void k_gemm_split(const float* __restrict__ X,
                                                    const float* __restrict__ W,
                                                    float* __restrict__ part) {
    __shared__ float xs[256][36];
    __shared__ float2 red[8][64][4];
    const int t = threadIdx.x;
    const int wv = t >> 6, ln = t & 63;
    const int e = blockIdx.x * 128 + ln * 2;
    const int h0 = blockIdx.y * 256;

    {   // stage X[0..32)[h0..h0+256) -> xs[hl][b]
        const int bs = t >> 3, hs = (t & 7) * 32;
#pragma unroll
        for (int i = 0; i < 8; ++i) {
            const float4 v = *(const float4*)&X[(size_t)bs * HID + h0 + hs + i * 4];
            xs[hs + i * 4 + 0][bs] = v.x;
            xs[hs + i * 4 + 1][bs] = v.y;
            xs[hs + i * 4 + 2][bs] = v.z;
            xs[hs + i * 4 + 3][bs] = v.w;
        }
    }
    __syncthreads();

    float2 acc[32];
#pragma unroll
    for (int i = 0; i < 32; ++i) acc[i] = make_float2(0.f, 0.f);

    const float* Wp = W + (size_t)(h0 + wv * 64) * E + e;
    const int hl0 = wv * 64;
    for (int hh = 0; hh < 64; ++hh) {
        const float2 w2 = *(const float2*)Wp;
        Wp += E;
#pragma unroll
        for (int i = 0; i < 8; ++i) {
            const float4 xv = *(const float4*)&xs[hl0 + hh][i * 4];
            acc[i * 4 + 0].x = fmaf(xv.x, w2.x, acc[i * 4 + 0].x);
            acc[i * 4 + 0].y = fmaf(xv.x, w2.y, acc[i * 4 + 0].y);
            acc[i * 4 + 1].x = fmaf(xv.y, w2.x, acc[i * 4 + 1].x);
            acc[i * 4 + 1].y = fmaf(xv.y, w2.y, acc[i * 4 + 1].y);
            acc[i * 4 + 2].x = fmaf(xv.z, w2.x, acc[i * 4 + 2].x);
            acc[i * 4 + 2].y = fmaf(xv.z, w2.y, acc[i * 4 + 2].y);
            acc[i * 4 + 3].x = fmaf(xv.w, w2.x, acc[i * 4 + 3].x);
            acc[i * 4 + 3].y = fmaf(xv.w, w2.y, acc[i * 4 + 3].y);
        }
    }

    for (int r = 0; r < 4; ++r) {
#pragma unroll
        for (int j = 0; j < 8; ++j) red[j][ln][wv] = acc[r * 8 + j];
        __syncthreads();
#pragma unroll
        for (int it = 0; it < 2; ++it) {
            const int item = t + it * 256;
            const int ln2 = item & 63, j2 = item >> 6;
            const float2 a0 = red[j2][ln2][0], a1 = red[j2][ln2][1];
            const float2 a2 = red[j2][ln2][2], a3 = red[j2][ln2][3];
            const float2 s = make_float2((a0.x + a1.x) + (a2.x + a3.x),
                                         (a0.y + a1.y) + (a2.y + a3.y));
            const int b2 = r * 8 + j2;
            const int e2 = blockIdx.x * 128 + ln2 * 2;
            *(float2*)(part + ((size_t)blockIdx.y * 32 + b2) * E + e2) = s;
        }
        __syncthreads();
    }
}

// ---------------- reduce NCH partial chunks (fp32 out) ----------------
__global__ void k_reduce_f32(const float* __restrict__ part,
                             float* __restrict__ out, const int n) {
    const int i4 = (blockIdx.x * 256 + threadIdx.x) * 4;
    if (i4 >= n) return;
    float4 s = make_float4(0.f, 0.f, 0.f, 0.f);
#pragma unroll
    for (int c = 0; c < NCH; ++c) {
        const float4 p = *(const float4*)(part + (size_t)c * n + i4);
        s.x += p.x; s.y += p.y; s.z += p.z; s.w += p.w;
    }
    *(float4*)(out + i4) = s;
}

// ---------------- rope: dense DxD rotation of q and k ----------------
__global__ void k_rope(const float* __restrict__ xqkv, const float* __restrict__ R,
                       float* __restrict__ q_rot, float* __restrict__ k_rot) {
    const int bid = blockIdx.x;
    const int b = bid / (NH + NKV);
    const int hd = bid % (NH + NKV);
    const float* src; float* dst;
    if (hd < NH) {
        src = xqkv + (size_t)b * EQKV + hd * D;
        dst = q_rot + ((size_t)b * NH + hd) * D;
    } else {
        const int kv = hd - NH;
        src = xqkv + (size_t)b * EQKV + NH * D + kv * D;
        dst = k_rot + ((size_t)b * NKV + kv) * D;
    }
    const int e = threadIdx.x;
    float acc = 0.f;
    for (int d = 0; d < D; ++d) acc = fmaf(src[d], R[(size_t)d * D + e], acc);
    dst[e] = acc;
}

// ------- flash-decode attention partial: one block per (b, kv, chunk) -------
__global__ __launch_bounds__(512) void k_attn_part(
        const float* __restrict__ q_rot, const float* __restrict__ k_rot,
        const float* __restrict__ xqkv,
        const float* __restrict__ cache_k, const float* __restrict__ cache_v,
        const int* __restrict__ p_start, const int* __restrict__ p_cur,
        float* __restrict__ pacc, float* __restrict__ pm, float* __restrict__ psum) {
    __shared__ float qs[4 * D];
    __shared__ float kn[D];
    __shared__ float vn[D];
    __shared__ float S[4 * CLEN];
    __shared__ float sm_m[4], sm_s[4];
    __shared__ float red[8 * 4 * D];

    const int t = threadIdx.x;
    const int bid = blockIdx.x;
    const int bkv = bid >> 2, c = bid & (NCHK - 1);
    const int b = bkv >> 3, kv = bkv & 7;
    const int l = t & 63, w = t >> 6;
    const int ls = min(p_start[0] + 1, WIN);
    const int cur = p_cur[0];
    const int p0 = c * CLEN;
    const int pend = min(ls, p0 + CLEN);
    const int cnt = pend - p0;              // may be <= 0 (empty chunk)

    {   // stage q (4 heads), new k, new v
        const int g = t >> 7, d = t & 127;
        qs[g * D + d] = q_rot[(((size_t)b * NH) + kv * GQ + g) * D + d];
        if (t < 128) kn[t] = k_rot[((size_t)b * NKV + kv) * D + t];
        else if (t < 256) {
            const int d2 = t - 128;
            vn[d2] = xqkv[(size_t)b * EQKV + (NH + NKV) * D + kv * D + d2];
        }
    }
    __syncthreads();

    const float scale = 0.08838834764831845f;   // 1/sqrt(128)
    const size_t base = (size_t)bkv * WIN * D;

    // ---- pass 1: scores for this chunk. 16 lanes per row p, lane owns 8 d. ----
    {
        const int sub = l & 15, r = l >> 4;
        const int d0 = sub * 8;
        float qreg[4][8];
#pragma unroll
        for (int g = 0; g < 4; ++g)
#pragma unroll
            for (int j = 0; j < 8; ++j) qreg[g][j] = qs[g * D + d0 + j];
        for (int it = 0; it < CLEN / 32; ++it) {
            const int p = p0 + it * 32 + w * 4 + r;
            if (p < pend) {
                const float4 a = *(const float4*)(cache_k + base + (size_t)p * D + d0);
                const float4 cc = *(const float4*)(cache_k + base + (size_t)p * D + d0 + 4);
                const float kk[8] = {a.x, a.y, a.z, a.w, cc.x, cc.y, cc.z, cc.w};
                float s4[4] = {0.f, 0.f, 0.f, 0.f};
#pragma unroll
                for (int g = 0; g < 4; ++g)
#pragma unroll
                    for (int j = 0; j < 8; ++j) s4[g] = fmaf(qreg[g][j], kk[j], s4[g]);
#pragma unroll
                for (int off = 1; off < 16; off <<= 1)
#pragma unroll
                    for (int g = 0; g < 4; ++g) s4[g] += __shfl_xor(s4[g], off, 16);
                if (sub == 0) {
                    const int pl = p - p0;
                    S[0 * CLEN + pl] = s4[0] * scale;
                    S[1 * CLEN + pl] = s4[1] * scale;
                    S[2 * CLEN + pl] = s4[2] * scale;
                    S[3 * CLEN + pl] = s4[3] * scale;
                }
            }
        }
    }
    __syncthreads();

    // ---- patch position cur with the NEW k (reference overwrites cache) ----
    if (cur >= p0 && cur < pend && t < 4) {
        float a = 0.f;
        for (int d = 0; d < D; ++d) a = fmaf(qs[t * D + d], kn[d], a);
        S[t * CLEN + cur - p0] = a * scale;
    }
    __syncthreads();

    // ---- partial softmax (waves 0..3, one per g): m_c, sum_c; S <- exp ----
    if (w < 4) {
        float m = -1e30f;
        for (int p = l; p < cnt; p += 64) m = fmaxf(m, S[w * CLEN + p]);
#pragma unroll
        for (int off = 32; off; off >>= 1) m = fmaxf(m, __shfl_xor(m, off, 64));
        float sum = 0.f;
        for (int p = l; p < cnt; p += 64) {
            const float e = __expf(S[w * CLEN + p] - m);
            S[w * CLEN + p] = e;
            sum += e;
        }
#pragma unroll
        for (int off = 32; off; off >>= 1) sum += __shfl_xor(sum, off, 64);
        if (l == 0) { sm_m[w] = m; sm_s[w] = sum; }
    }
    __syncthreads();

    // ---- pass 2: PV over this chunk (unnormalized). ----
    {
        const int s = t & 15, pt = t >> 4;
        const int d0 = s * 8;
        float vn8[8];
#pragma unroll
        for (int j = 0; j < 8; ++j) vn8[j] = vn[d0 + j];
        float acc[4][8];
#pragma unroll
        for (int g = 0; g < 4; ++g)
#pragma unroll
            for (int j = 0; j < 8; ++j) acc[g][j] = 0.f;
        for (int i = 0; i < CLEN / 32; ++i) {
            const int p = p0 + i * 32 + pt;
            if (p < pend) {
                const float4 a = *(const float4*)(cache_v + base + (size_t)p * D + d0);
                const float4 cc = *(const float4*)(cache_v + base + (size_t)p * D + d0 + 4);
                float vv[8] = {a.x, a.y, a.z, a.w, cc.x, cc.y, cc.z, cc.w};
                if (p == cur) {
#pragma unroll
                    for (int j = 0; j < 8; ++j) vv[j] = vn8[j];
                }
                const int pl = p - p0;
                const float s0 = S[0 * CLEN + pl], s1 = S[1 * CLEN + pl];
                const float s2 = S[2 * CLEN + pl], s3 = S[3 * CLEN + pl];
#pragma unroll
                for (int j = 0; j < 8; ++j) {
                    acc[0][j] = fmaf(s0, vv[j], acc[0][j]);
                    acc[1][j] = fmaf(s1, vv[j], acc[1][j]);
                    acc[2][j] = fmaf(s2, vv[j], acc[2][j]);
                    acc[3][j] = fmaf(s3, vv[j], acc[3][j]);
                }
            }
        }
#pragma unroll
        for (int off = 16; off <= 32; off <<= 1)
#pragma unroll
            for (int g = 0; g < 4; ++g)
#pragma unroll
                for (int j = 0; j < 8; ++j)
                    acc[g][j] += __shfl_xor(acc[g][j], off, 64);
        if (l < 16) {
#pragma unroll
            for (int g = 0; g < 4; ++g)
#pragma unroll
                for (int j = 0; j < 8; ++j)
                    red[(w * 4 + g) * D + l * 8 + j] = acc[g][j];
        }
    }
    __syncthreads();

    {   // cross-wave reduce + write partials
        const int g = t >> 7, d = t & 127;
        float sum = 0.f;
#pragma unroll
        for (int w8 = 0; w8 < 8; ++w8) sum += red[(w8 * 4 + g) * D + d];
        const int hidx = bkv * GQ + g;
        pacc[((size_t)hidx * NCHK + c) * D + d] = sum;
        if (d == 0) {
            pm[hidx * NCHK + c]   = sm_m[g];
            psum[hidx * NCHK + c] = sm_s[g];
        }
    }
}

// ------- combine partial chunks: one block per (b, kv), 512 threads -------
__global__ __launch_bounds__(512) void k_attn_combine(
        const float* __restrict__ pacc, const float* __restrict__ pm,
        const float* __restrict__ psum, float* __restrict__ attn_out) {
    const int t = threadIdx.x;
    const int bkv = blockIdx.x;
    const int b = bkv >> 3, kv = bkv & 7;
    const int g = t >> 7, d = t & 127;
    const int hidx = bkv * GQ + g;

    float mm[NCHK];
    float m = -1e30f;
#pragma unroll
    for (int c = 0; c < NCHK; ++c) {
        mm[c] = pm[hidx * NCHK + c];
        m = fmaxf(m, mm[c]);
    }
    float tot = 0.f, acc = 0.f;
#pragma unroll
    for (int c = 0; c < NCHK; ++c) {
        const float wgt = __expf(mm[c] - m);
        tot = fmaf(psum[hidx * NCHK + c], wgt, tot);
        acc = fmaf(pacc[((size_t)hidx * NCHK + c) * D + d], wgt, acc);
    }
    attn_out[(size_t)b * HID + (kv * GQ + g) * D + d] = acc / tot;
}

// ---------------- host launch ----------------
extern "C" void kernel_launch(void* const* d_in, const int* in_sizes, int n_in,
                              void* d_out, int out_size, void* d_ws, size_t ws_size,
                              hipStream_t stream) {
    const float* x    = (const float*)d_in[0];
    const float* wqkv = (const float*)d_in[1];
    const float* wo   = (const float*)d_in[2];
    const float* rot  = (const float*)d_in[3];
    const float* ck   = (const float*)d_in[4];
    const float* cv   = (const float*)d_in[5];
    const int*   sp   = (const int*)d_in[6];
    const int*   cp   = (const int*)d_in[7];

    float* ws     = (float*)d_ws;
    float* xqkv_o = ws;                     // 32*6144   = 196608
    float* q_rot  = ws + 196608;            // 32*32*128 = 131072
    float* k_rot  = ws + 327680;            // 32*8*128  = 32768
    float* attn_o = ws + 360448;            // 32*4096   = 131072
    float* part   = ws + 491520;            // NCH*32*6144 = 3145728 (GEMM partials)
    // attention partials alias the part region (disjoint in time):
    float* pacc   = part;                   // 256*4*4*128 = 524288
    float* pm     = part + 524288;          // 4096
    float* psum   = part + 528384;          // 4096

    k_gemm_split<EQKV><<<dim3(EQKV / 128, NCH), 256, 0, stream>>>(x, wqkv, part);
    k_reduce_f32<<<192, 256, 0, stream>>>(part, xqkv_o, 32 * EQKV);
    k_rope<<<32 * (NH + NKV), 128, 0, stream>>>(xqkv_o, rot, q_rot, k_rot);
    k_attn_part<<<256 * NCHK, 512, 0, stream>>>(q_rot, k_rot, xqkv_o, ck, cv,
                                                sp, cp, pacc, pm, psum);
    k_attn_combine<<<256, 512, 0, stream>>>(pacc, pm, psum, attn_o);
    k_gemm_split<HID><<<dim3(HID / 128, NCH), 256, 0, stream>>>(attn_o, wo, part);
    k_reduce_f32<<<128, 256, 0, stream>>>(part, (float*)d_out, 32 * HID);
}

// Round 7
// 181.079 us; speedup vs baseline: 3.9849x; 1.0546x over previous
//
#include <hip/hip_runtime.h>
#include <hip/hip_bf16.h>

#define HID 4096
#define EQKV 6144
#define NH 32
#define NKV 8
#define GQ 4
#define D 128
#define WIN 2048
#define NCH 16   // K-chunks for split-K GEMM (4096 / 256)
#define NCHK 4   // position chunks for flash-decode attention
#define CLEN (WIN / NCHK)   // 512

// ------- split-K GEMM: part[chunk][b][e] = sum_{h in chunk} X[b][h] * W[h][e]
template<int E>
__global__ __launch_bounds__(256) void k_gemm_split(const float* __restrict__ X,
                                                    const float* __restrict__ W,
                                                    float* __restrict__ part) {
    __shared__ float xs[256][36];
    __shared__ float2 red[8][64][4];
    const int t = threadIdx.x;
    const int wv = t >> 6, ln = t & 63;
    const int e = blockIdx.x * 128 + ln * 2;
    const int h0 = blockIdx.y * 256;

    {   // stage X[0..32)[h0..h0+256) -> xs[hl][b]
        const int bs = t >> 3, hs = (t & 7) * 32;
#pragma unroll
        for (int i = 0; i < 8; ++i) {
            const float4 v = *(const float4*)&X[(size_t)bs * HID + h0 + hs + i * 4];
            xs[hs + i * 4 + 0][bs] = v.x;
            xs[hs + i * 4 + 1][bs] = v.y;
            xs[hs + i * 4 + 2][bs] = v.z;
            xs[hs + i * 4 + 3][bs] = v.w;
        }
    }
    __syncthreads();

    float2 acc[32];
#pragma unroll
    for (int i = 0; i < 32; ++i) acc[i] = make_float2(0.f, 0.f);

    const float* Wp = W + (size_t)(h0 + wv * 64) * E + e;
    const int hl0 = wv * 64;
    for (int hh = 0; hh < 64; ++hh) {
        const float2 w2 = *(const float2*)Wp;
        Wp += E;
#pragma unroll
        for (int i = 0; i < 8; ++i) {
            const float4 xv = *(const float4*)&xs[hl0 + hh][i * 4];
            acc[i * 4 + 0].x = fmaf(xv.x, w2.x, acc[i * 4 + 0].x);
            acc[i * 4 + 0].y = fmaf(xv.x, w2.y, acc[i * 4 + 0].y);
            acc[i * 4 + 1].x = fmaf(xv.y, w2.x, acc[i * 4 + 1].x);
            acc[i * 4 + 1].y = fmaf(xv.y, w2.y, acc[i * 4 + 1].y);
            acc[i * 4 + 2].x = fmaf(xv.z, w2.x, acc[i * 4 + 2].x);
            acc[i * 4 + 2].y = fmaf(xv.z, w2.y, acc[i * 4 + 2].y);
            acc[i * 4 + 3].x = fmaf(xv.w, w2.x, acc[i * 4 + 3].x);
            acc[i * 4 + 3].y = fmaf(xv.w, w2.y, acc[i * 4 + 3].y);
        }
    }

    for (int r = 0; r < 4; ++r) {
#pragma unroll
        for (int j = 0; j < 8; ++j) red[j][ln][wv] = acc[r * 8 + j];
        __syncthreads();
#pragma unroll
        for (int it = 0; it < 2; ++it) {
            const int item = t + it * 256;
            const int ln2 = item & 63, j2 = item >> 6;
            const float2 a0 = red[j2][ln2][0], a1 = red[j2][ln2][1];
            const float2 a2 = red[j2][ln2][2], a3 = red[j2][ln2][3];
            const float2 s = make_float2((a0.x + a1.x) + (a2.x + a3.x),
                                         (a0.y + a1.y) + (a2.y + a3.y));
            const int b2 = r * 8 + j2;
            const int e2 = blockIdx.x * 128 + ln2 * 2;
            *(float2*)(part + ((size_t)blockIdx.y * 32 + b2) * E + e2) = s;
        }
        __syncthreads();
    }
}

// ---------------- reduce NCH partial chunks (fp32 out) ----------------
__global__ void k_reduce_f32(const float* __restrict__ part,
                             float* __restrict__ out, const int n) {
    const int i4 = (blockIdx.x * 256 + threadIdx.x) * 4;
    if (i4 >= n) return;
    float4 s = make_float4(0.f, 0.f, 0.f, 0.f);
#pragma unroll
    for (int c = 0; c < NCH; ++c) {
        const float4 p = *(const float4*)(part + (size_t)c * n + i4);
        s.x += p.x; s.y += p.y; s.z += p.z; s.w += p.w;
    }
    *(float4*)(out + i4) = s;
}

// ---------------- rope: dense DxD rotation of q and k ----------------
__global__ void k_rope(const float* __restrict__ xqkv, const float* __restrict__ R,
                       float* __restrict__ q_rot, float* __restrict__ k_rot) {
    const int bid = blockIdx.x;
    const int b = bid / (NH + NKV);
    const int hd = bid % (NH + NKV);
    const float* src; float* dst;
    if (hd < NH) {
        src = xqkv + (size_t)b * EQKV + hd * D;
        dst = q_rot + ((size_t)b * NH + hd) * D;
    } else {
        const int kv = hd - NH;
        src = xqkv + (size_t)b * EQKV + NH * D + kv * D;
        dst = k_rot + ((size_t)b * NKV + kv) * D;
    }
    const int e = threadIdx.x;
    float acc = 0.f;
    for (int d = 0; d < D; ++d) acc = fmaf(src[d], R[(size_t)d * D + e], acc);
    dst[e] = acc;
}

// ------- flash-decode attention partial: one block per (b, kv, chunk) -------
__global__ __launch_bounds__(512) void k_attn_part(
        const float* __restrict__ q_rot, const float* __restrict__ k_rot,
        const float* __restrict__ xqkv,
        const float* __restrict__ cache_k, const float* __restrict__ cache_v,
        const int* __restrict__ p_start, const int* __restrict__ p_cur,
        float* __restrict__ pacc, float* __restrict__ pm, float* __restrict__ psum) {
    __shared__ float qs[4 * D];
    __shared__ float kn[D];
    __shared__ float vn[D];
    __shared__ float S[4 * CLEN];
    __shared__ float sm_m[4], sm_s[4];
    __shared__ float red[8 * 4 * D];

    const int t = threadIdx.x;
    const int bid = blockIdx.x;
    const int bkv = bid >> 2, c = bid & (NCHK - 1);
    const int b = bkv >> 3, kv = bkv & 7;
    const int l = t & 63, w = t >> 6;
    const int ls = min(p_start[0] + 1, WIN);
    const int cur = p_cur[0];
    const int p0 = c * CLEN;
    const int pend = min(ls, p0 + CLEN);
    const int cnt = pend - p0;
    const bool full = (cnt == CLEN);

    {   // stage q (4 heads), new k, new v
        const int g = t >> 7, d = t & 127;
        qs[g * D + d] = q_rot[(((size_t)b * NH) + kv * GQ + g) * D + d];
        if (t < 128) kn[t] = k_rot[((size_t)b * NKV + kv) * D + t];
        else if (t < 256) {
            const int d2 = t - 128;
            vn[d2] = xqkv[(size_t)b * EQKV + (NH + NKV) * D + kv * D + d2];
        }
    }
    __syncthreads();

    const float scale = 0.08838834764831845f;   // 1/sqrt(128)
    const size_t base = (size_t)bkv * WIN * D;
    const size_t step = (size_t)32 * D;

    // ---- pass 1: scores. 16 lanes per row, lane owns 8 d's. ----
    {
        const int sub = l & 15, r = l >> 4;
        const int d0 = sub * 8;
        float qreg[4][8];
#pragma unroll
        for (int g = 0; g < 4; ++g)
#pragma unroll
            for (int j = 0; j < 8; ++j) qreg[g][j] = qs[g * D + d0 + j];

        if (full) {
            // branchless + 1-deep prefetch
            const float* kp = cache_k + base + (size_t)(p0 + w * 4 + r) * D + d0;
            float4 A = *(const float4*)kp;
            float4 C = *(const float4*)(kp + 4);
            int pl = w * 4 + r;
            for (int it = 0; it < CLEN / 32; ++it) {
                const float4 a = A, cc = C;
                kp += step;
                if (it + 1 < CLEN / 32) {
                    A = *(const float4*)kp;
                    C = *(const float4*)(kp + 4);
                }
                const float kk[8] = {a.x, a.y, a.z, a.w, cc.x, cc.y, cc.z, cc.w};
                float s4[4] = {0.f, 0.f, 0.f, 0.f};
#pragma unroll
                for (int g = 0; g < 4; ++g)
#pragma unroll
                    for (int j = 0; j < 8; ++j) s4[g] = fmaf(qreg[g][j], kk[j], s4[g]);
#pragma unroll
                for (int off = 1; off < 16; off <<= 1)
#pragma unroll
                    for (int g = 0; g < 4; ++g) s4[g] += __shfl_xor(s4[g], off, 16);
                if (sub == 0) {
                    S[0 * CLEN + pl] = s4[0] * scale;
                    S[1 * CLEN + pl] = s4[1] * scale;
                    S[2 * CLEN + pl] = s4[2] * scale;
                    S[3 * CLEN + pl] = s4[3] * scale;
                }
                pl += 32;
            }
        } else {
            for (int it = 0; it < CLEN / 32; ++it) {
                const int p = p0 + it * 32 + w * 4 + r;
                if (p < pend) {
                    const float4 a = *(const float4*)(cache_k + base + (size_t)p * D + d0);
                    const float4 cc = *(const float4*)(cache_k + base + (size_t)p * D + d0 + 4);
                    const float kk[8] = {a.x, a.y, a.z, a.w, cc.x, cc.y, cc.z, cc.w};
                    float s4[4] = {0.f, 0.f, 0.f, 0.f};
#pragma unroll
                    for (int g = 0; g < 4; ++g)
#pragma unroll
                        for (int j = 0; j < 8; ++j) s4[g] = fmaf(qreg[g][j], kk[j], s4[g]);
#pragma unroll
                    for (int off = 1; off < 16; off <<= 1)
#pragma unroll
                        for (int g = 0; g < 4; ++g) s4[g] += __shfl_xor(s4[g], off, 16);
                    if (sub == 0) {
                        const int pl = p - p0;
                        S[0 * CLEN + pl] = s4[0] * scale;
                        S[1 * CLEN + pl] = s4[1] * scale;
                        S[2 * CLEN + pl] = s4[2] * scale;
                        S[3 * CLEN + pl] = s4[3] * scale;
                    }
                }
            }
        }
    }
    __syncthreads();

    // ---- patch position cur with the NEW k (reference overwrites cache) ----
    if (cur >= p0 && cur < pend && t < 4) {
        float a = 0.f;
        for (int d = 0; d < D; ++d) a = fmaf(qs[t * D + d], kn[d], a);
        S[t * CLEN + cur - p0] = a * scale;
    }
    __syncthreads();

    // ---- partial softmax (waves 0..3, one per g): m_c, sum_c; S <- exp ----
    if (w < 4) {
        float m = -1e30f;
        for (int p = l; p < cnt; p += 64) m = fmaxf(m, S[w * CLEN + p]);
#pragma unroll
        for (int off = 32; off; off >>= 1) m = fmaxf(m, __shfl_xor(m, off, 64));
        float sum = 0.f;
        for (int p = l; p < cnt; p += 64) {
            const float e = __expf(S[w * CLEN + p] - m);
            S[w * CLEN + p] = e;
            sum += e;
        }
#pragma unroll
        for (int off = 32; off; off >>= 1) sum += __shfl_xor(sum, off, 64);
        if (l == 0) { sm_m[w] = m; sm_s[w] = sum; }
    }
    __syncthreads();

    // ---- pass 2: PV (unnormalized). thread owns 8 d's, strides p by 32. ----
    {
        const int s = t & 15, pt = t >> 4;
        const int d0 = s * 8;
        float acc[4][8];
#pragma unroll
        for (int g = 0; g < 4; ++g)
#pragma unroll
            for (int j = 0; j < 8; ++j) acc[g][j] = 0.f;

        if (full) {
            const float* vp = cache_v + base + (size_t)(p0 + pt) * D + d0;
            float4 A = *(const float4*)vp;
            float4 C = *(const float4*)(vp + 4);
            int pl = pt;
            for (int it = 0; it < CLEN / 32; ++it) {
                const float4 a = A, cc = C;
                vp += step;
                if (it + 1 < CLEN / 32) {
                    A = *(const float4*)vp;
                    C = *(const float4*)(vp + 4);
                }
                const float vv[8] = {a.x, a.y, a.z, a.w, cc.x, cc.y, cc.z, cc.w};
                const float s0 = S[0 * CLEN + pl], s1 = S[1 * CLEN + pl];
                const float s2 = S[2 * CLEN + pl], s3 = S[3 * CLEN + pl];
#pragma unroll
                for (int j = 0; j < 8; ++j) {
                    acc[0][j] = fmaf(s0, vv[j], acc[0][j]);
                    acc[1][j] = fmaf(s1, vv[j], acc[1][j]);
                    acc[2][j] = fmaf(s2, vv[j], acc[2][j]);
                    acc[3][j] = fmaf(s3, vv[j], acc[3][j]);
                }
                pl += 32;
            }
            // post-hoc fix of position cur: acc += S[cur]*(vn - v_cached)
            if (cur >= p0 && cur < pend && pt == ((cur - p0) & 31)) {
                const float* vc = cache_v + base + (size_t)cur * D + d0;
                const float4 a = *(const float4*)vc;
                const float4 cc = *(const float4*)(vc + 4);
                const float vv[8] = {a.x, a.y, a.z, a.w, cc.x, cc.y, cc.z, cc.w};
                const int pl2 = cur - p0;
                const float s0 = S[0 * CLEN + pl2], s1 = S[1 * CLEN + pl2];
                const float s2 = S[2 * CLEN + pl2], s3 = S[3 * CLEN + pl2];
#pragma unroll
                for (int j = 0; j < 8; ++j) {
                    const float dv = vn[d0 + j] - vv[j];
                    acc[0][j] = fmaf(s0, dv, acc[0][j]);
                    acc[1][j] = fmaf(s1, dv, acc[1][j]);
                    acc[2][j] = fmaf(s2, dv, acc[2][j]);
                    acc[3][j] = fmaf(s3, dv, acc[3][j]);
                }
            }
        } else {
            float vn8[8];
#pragma unroll
            for (int j = 0; j < 8; ++j) vn8[j] = vn[d0 + j];
            for (int i = 0; i < CLEN / 32; ++i) {
                const int p = p0 + i * 32 + pt;
                if (p < pend) {
                    const float4 a = *(const float4*)(cache_v + base + (size_t)p * D + d0);
                    const float4 cc = *(const float4*)(cache_v + base + (size_t)p * D + d0 + 4);
                    float vv[8] = {a.x, a.y, a.z, a.w, cc.x, cc.y, cc.z, cc.w};
                    if (p == cur) {
#pragma unroll
                        for (int j = 0; j < 8; ++j) vv[j] = vn8[j];
                    }
                    const int pl = p - p0;
                    const float s0 = S[0 * CLEN + pl], s1 = S[1 * CLEN + pl];
                    const float s2 = S[2 * CLEN + pl], s3 = S[3 * CLEN + pl];
#pragma unroll
                    for (int j = 0; j < 8; ++j) {
                        acc[0][j] = fmaf(s0, vv[j], acc[0][j]);
                        acc[1][j] = fmaf(s1, vv[j], acc[1][j]);
                        acc[2][j] = fmaf(s2, vv[j], acc[2][j]);
                        acc[3][j] = fmaf(s3, vv[j], acc[3][j]);
                    }
                }
            }
        }
#pragma unroll
        for (int off = 16; off <= 32; off <<= 1)
#pragma unroll
            for (int g = 0; g < 4; ++g)
#pragma unroll
                for (int j = 0; j < 8; ++j)
                    acc[g][j] += __shfl_xor(acc[g][j], off, 64);
        if (l < 16) {
#pragma unroll
            for (int g = 0; g < 4; ++g)
#pragma unroll
                for (int j = 0; j < 8; ++j)
                    red[(w * 4 + g) * D + l * 8 + j] = acc[g][j];
        }
    }
    __syncthreads();

    {   // cross-wave reduce + write partials
        const int g = t >> 7, d = t & 127;
        float sum = 0.f;
#pragma unroll
        for (int w8 = 0; w8 < 8; ++w8) sum += red[(w8 * 4 + g) * D + d];
        const int hidx = bkv * GQ + g;
        pacc[((size_t)hidx * NCHK + c) * D + d] = sum;
        if (d == 0) {
            pm[hidx * NCHK + c]   = sm_m[g];
            psum[hidx * NCHK + c] = sm_s[g];
        }
    }
}

// ------- combine partial chunks: one block per (b, kv), 512 threads -------
__global__ __launch_bounds__(512) void k_attn_combine(
        const float* __restrict__ pacc, const float* __restrict__ pm,
        const float* __restrict__ psum, float* __restrict__ attn_out) {
    const int t = threadIdx.x;
    const int bkv = blockIdx.x;
    const int b = bkv >> 3, kv = bkv & 7;
    const int g = t >> 7, d = t & 127;
    const int hidx = bkv * GQ + g;

    float mm[NCHK];
    float m = -1e30f;
#pragma unroll
    for (int c = 0; c < NCHK; ++c) {
        mm[c] = pm[hidx * NCHK + c];
        m = fmaxf(m, mm[c]);
    }
    float tot = 0.f, acc = 0.f;
#pragma unroll
    for (int c = 0; c < NCHK; ++c) {
        const float wgt = __expf(mm[c] - m);
        tot = fmaf(psum[hidx * NCHK + c], wgt, tot);
        acc = fmaf(pacc[((size_t)hidx * NCHK + c) * D + d], wgt, acc);
    }
    attn_out[(size_t)b * HID + (kv * GQ + g) * D + d] = acc / tot;
}

// ---------------- host launch ----------------
extern "C" void kernel_launch(void* const* d_in, const int* in_sizes, int n_in,
                              void* d_out, int out_size, void* d_ws, size_t ws_size,
                              hipStream_t stream) {
    const float* x    = (const float*)d_in[0];
    const float* wqkv = (const float*)d_in[1];
    const float* wo   = (const float*)d_in[2];
    const float* rot  = (const float*)d_in[3];
    const float* ck   = (const float*)d_in[4];
    const float* cv   = (const float*)d_in[5];
    const int*   sp   = (const int*)d_in[6];
    const int*   cp   = (const int*)d_in[7];

    float* ws     = (float*)d_ws;
    float* xqkv_o = ws;                     // 32*6144   = 196608
    float* q_rot  = ws + 196608;            // 32*32*128 = 131072
    float* k_rot  = ws + 327680;            // 32*8*128  = 32768
    float* attn_o = ws + 360448;            // 32*4096   = 131072
    float* part   = ws + 491520;            // NCH*32*6144 = 3145728 (GEMM partials)
    // attention partials alias the part region (disjoint in time):
    float* pacc   = part;                   // 256*4*4*128 = 524288
    float* pm     = part + 524288;          // 4096
    float* psum   = part + 528384;          // 4096

    k_gemm_split<EQKV><<<dim3(EQKV / 128, NCH), 256, 0, stream>>>(x, wqkv, part);
    k_reduce_f32<<<192, 256, 0, stream>>>(part, xqkv_o, 32 * EQKV);
    k_rope<<<32 * (NH + NKV), 128, 0, stream>>>(xqkv_o, rot, q_rot, k_rot);
    k_attn_part<<<256 * NCHK, 512, 0, stream>>>(q_rot, k_rot, xqkv_o, ck, cv,
                                                sp, cp, pacc, pm, psum);
    k_attn_combine<<<256, 512, 0, stream>>>(pacc, pm, psum, attn_o);
    k_gemm_split<HID><<<dim3(HID / 128, NCH), 256, 0, stream>>>(attn_o, wo, part);
    k_reduce_f32<<<128, 256, 0, stream>>>(part, (float*)d_out, 32 * HID);
}

// Round 8
// 175.895 us; speedup vs baseline: 4.1023x; 1.0295x over previous
//
#include <hip/hip_runtime.h>
#include <hip/hip_bf16.h>

#define HID 4096
#define EQKV 6144
#define NH 32
#define NKV 8
#define GQ 4
#define D 128
#define WIN 2048
#define NCH 16   // K-chunks for split-K GEMM (4096 / 256)
#define NCHK 8   // position chunks for flash-decode attention
#define CLEN (WIN / NCHK)   // 256

// ------- split-K GEMM: part[chunk][b][e] = sum_{h in chunk} X[b][h] * W[h][e]
// 4-deep W row prefetch: ~2KB in flight per wave.
template<int E>
__global__ __launch_bounds__(256) void k_gemm_split(const float* __restrict__ X,
                                                    const float* __restrict__ W,
                                                    float* __restrict__ part) {
    __shared__ float xs[256][36];
    __shared__ float2 red[8][64][4];
    const int t = threadIdx.x;
    const int wv = t >> 6, ln = t & 63;
    const int e = blockIdx.x * 128 + ln * 2;
    const int h0 = blockIdx.y * 256;

    {   // stage X[0..32)[h0..h0+256) -> xs[hl][b]
        const int bs = t >> 3, hs = (t & 7) * 32;
#pragma unroll
        for (int i = 0; i < 8; ++i) {
            const float4 v = *(const float4*)&X[(size_t)bs * HID + h0 + hs + i * 4];
            xs[hs + i * 4 + 0][bs] = v.x;
            xs[hs + i * 4 + 1][bs] = v.y;
            xs[hs + i * 4 + 2][bs] = v.z;
            xs[hs + i * 4 + 3][bs] = v.w;
        }
    }
    __syncthreads();

    float2 acc[32];
#pragma unroll
    for (int i = 0; i < 32; ++i) acc[i] = make_float2(0.f, 0.f);

    const float* Wp = W + (size_t)(h0 + wv * 64) * E + e;
    const int hl0 = wv * 64;
    float2 wb[4];
#pragma unroll
    for (int i = 0; i < 4; ++i) wb[i] = *(const float2*)(Wp + (size_t)i * E);
    Wp += (size_t)4 * E;

    for (int hh = 0; hh < 64; hh += 4) {
        float2 wc[4];
#pragma unroll
        for (int i = 0; i < 4; ++i) wc[i] = wb[i];
        if (hh + 4 < 64) {
#pragma unroll
            for (int i = 0; i < 4; ++i) wb[i] = *(const float2*)(Wp + (size_t)i * E);
            Wp += (size_t)4 * E;
        }
#pragma unroll
        for (int i = 0; i < 4; ++i) {
            const float wx = wc[i].x, wy = wc[i].y;
            const int row = hl0 + hh + i;
#pragma unroll
            for (int q = 0; q < 8; ++q) {
                const float4 xv = *(const float4*)&xs[row][q * 4];
                acc[q * 4 + 0].x = fmaf(xv.x, wx, acc[q * 4 + 0].x);
                acc[q * 4 + 0].y = fmaf(xv.x, wy, acc[q * 4 + 0].y);
                acc[q * 4 + 1].x = fmaf(xv.y, wx, acc[q * 4 + 1].x);
                acc[q * 4 + 1].y = fmaf(xv.y, wy, acc[q * 4 + 1].y);
                acc[q * 4 + 2].x = fmaf(xv.z, wx, acc[q * 4 + 2].x);
                acc[q * 4 + 2].y = fmaf(xv.z, wy, acc[q * 4 + 2].y);
                acc[q * 4 + 3].x = fmaf(xv.w, wx, acc[q * 4 + 3].x);
                acc[q * 4 + 3].y = fmaf(xv.w, wy, acc[q * 4 + 3].y);
            }
        }
    }

    for (int r = 0; r < 4; ++r) {
#pragma unroll
        for (int j = 0; j < 8; ++j) red[j][ln][wv] = acc[r * 8 + j];
        __syncthreads();
#pragma unroll
        for (int it = 0; it < 2; ++it) {
            const int item = t + it * 256;
            const int ln2 = item & 63, j2 = item >> 6;
            const float2 a0 = red[j2][ln2][0], a1 = red[j2][ln2][1];
            const float2 a2 = red[j2][ln2][2], a3 = red[j2][ln2][3];
            const float2 s = make_float2((a0.x + a1.x) + (a2.x + a3.x),
                                         (a0.y + a1.y) + (a2.y + a3.y));
            const int b2 = r * 8 + j2;
            const int e2 = blockIdx.x * 128 + ln2 * 2;
            *(float2*)(part + ((size_t)blockIdx.y * 32 + b2) * E + e2) = s;
        }
        __syncthreads();
    }
}

// ---------------- reduce NCH partial chunks (fp32 out) ----------------
__global__ void k_reduce_f32(const float* __restrict__ part,
                             float* __restrict__ out, const int n) {
    const int i4 = (blockIdx.x * 256 + threadIdx.x) * 4;
    if (i4 >= n) return;
    float4 s = make_float4(0.f, 0.f, 0.f, 0.f);
#pragma unroll
    for (int c = 0; c < NCH; ++c) {
        const float4 p = *(const float4*)(part + (size_t)c * n + i4);
        s.x += p.x; s.y += p.y; s.z += p.z; s.w += p.w;
    }
    *(float4*)(out + i4) = s;
}

// ---------------- rope: dense DxD rotation of q and k ----------------
__global__ void k_rope(const float* __restrict__ xqkv, const float* __restrict__ R,
                       float* __restrict__ q_rot, float* __restrict__ k_rot) {
    const int bid = blockIdx.x;
    const int b = bid / (NH + NKV);
    const int hd = bid % (NH + NKV);
    const float* src; float* dst;
    if (hd < NH) {
        src = xqkv + (size_t)b * EQKV + hd * D;
        dst = q_rot + ((size_t)b * NH + hd) * D;
    } else {
        const int kv = hd - NH;
        src = xqkv + (size_t)b * EQKV + NH * D + kv * D;
        dst = k_rot + ((size_t)b * NKV + kv) * D;
    }
    const int e = threadIdx.x;
    float acc = 0.f;
    for (int d = 0; d < D; d += 4) {
        const float r0 = R[(size_t)(d + 0) * D + e];
        const float r1 = R[(size_t)(d + 1) * D + e];
        const float r2 = R[(size_t)(d + 2) * D + e];
        const float r3 = R[(size_t)(d + 3) * D + e];
        acc = fmaf(src[d + 0], r0, acc);
        acc = fmaf(src[d + 1], r1, acc);
        acc = fmaf(src[d + 2], r2, acc);
        acc = fmaf(src[d + 3], r3, acc);
    }
    dst[e] = acc;
}

// ------- flash-decode attention partial: one block per (b, kv, chunk) -------
// 256 threads = 4 waves -> ~4 resident blocks/CU even at ~80 VGPR.
__global__ __launch_bounds__(256) void k_attn_part(
        const float* __restrict__ q_rot, const float* __restrict__ k_rot,
        const float* __restrict__ xqkv,
        const float* __restrict__ cache_k, const float* __restrict__ cache_v,
        const int* __restrict__ p_start, const int* __restrict__ p_cur,
        float* __restrict__ pacc, float* __restrict__ pm, float* __restrict__ psum) {
    __shared__ float qs[4 * D];
    __shared__ float kn[D];
    __shared__ float vn[D];
    __shared__ float S[4 * CLEN];
    __shared__ float sm_m[4], sm_s[4];
    __shared__ float red[4 * 4 * D];

    const int t = threadIdx.x;
    const int bid = blockIdx.x;
    const int bkv = bid >> 3, c = bid & (NCHK - 1);
    const int b = bkv >> 3, kv = bkv & 7;
    const int l = t & 63, w = t >> 6;       // w in 0..3
    const int ls = min(p_start[0] + 1, WIN);
    const int cur = p_cur[0];
    const int p0 = c * CLEN;
    const int pend = min(ls, p0 + CLEN);
    const int cnt = pend - p0;
    const bool full = (cnt == CLEN);

    {   // stage q (4 heads = 512 contiguous floats), new k, new v
        const float* qsrc = q_rot + ((size_t)b * NH + kv * GQ) * D;
        qs[t] = qsrc[t];
        qs[t + 256] = qsrc[t + 256];
        if (t < 128) kn[t] = k_rot[((size_t)b * NKV + kv) * D + t];
        else vn[t - 128] = xqkv[(size_t)b * EQKV + (NH + NKV) * D + kv * D + (t - 128)];
    }
    __syncthreads();

    const float scale = 0.08838834764831845f;   // 1/sqrt(128)
    const size_t base = (size_t)bkv * WIN * D;
    const size_t step = (size_t)16 * D;

    // ---- pass 1: scores. 16 lanes per row, lane owns 8 d's; 16 rows/iter. ----
    {
        const int sub = l & 15, r = l >> 4;
        const int d0 = sub * 8;
        float qreg[4][8];
#pragma unroll
        for (int g = 0; g < 4; ++g)
#pragma unroll
            for (int j = 0; j < 8; ++j) qreg[g][j] = qs[g * D + d0 + j];

        if (full) {
            const float* kp = cache_k + base + (size_t)(p0 + w * 4 + r) * D + d0;
            float4 A = *(const float4*)kp;
            float4 C = *(const float4*)(kp + 4);
            int pl = w * 4 + r;
            for (int it = 0; it < CLEN / 16; ++it) {
                const float4 a = A, cc = C;
                kp += step;
                if (it + 1 < CLEN / 16) {
                    A = *(const float4*)kp;
                    C = *(const float4*)(kp + 4);
                }
                const float kk[8] = {a.x, a.y, a.z, a.w, cc.x, cc.y, cc.z, cc.w};
                float s4[4] = {0.f, 0.f, 0.f, 0.f};
#pragma unroll
                for (int g = 0; g < 4; ++g)
#pragma unroll
                    for (int j = 0; j < 8; ++j) s4[g] = fmaf(qreg[g][j], kk[j], s4[g]);
#pragma unroll
                for (int off = 1; off < 16; off <<= 1)
#pragma unroll
                    for (int g = 0; g < 4; ++g) s4[g] += __shfl_xor(s4[g], off, 16);
                if (sub == 0) {
                    S[0 * CLEN + pl] = s4[0] * scale;
                    S[1 * CLEN + pl] = s4[1] * scale;
                    S[2 * CLEN + pl] = s4[2] * scale;
                    S[3 * CLEN + pl] = s4[3] * scale;
                }
                pl += 16;
            }
        } else {
            for (int it = 0; it < CLEN / 16; ++it) {
                const int p = p0 + it * 16 + w * 4 + r;
                if (p < pend) {
                    const float4 a = *(const float4*)(cache_k + base + (size_t)p * D + d0);
                    const float4 cc = *(const float4*)(cache_k + base + (size_t)p * D + d0 + 4);
                    const float kk[8] = {a.x, a.y, a.z, a.w, cc.x, cc.y, cc.z, cc.w};
                    float s4[4] = {0.f, 0.f, 0.f, 0.f};
#pragma unroll
                    for (int g = 0; g < 4; ++g)
#pragma unroll
                        for (int j = 0; j < 8; ++j) s4[g] = fmaf(qreg[g][j], kk[j], s4[g]);
#pragma unroll
                    for (int off = 1; off < 16; off <<= 1)
#pragma unroll
                        for (int g = 0; g < 4; ++g) s4[g] += __shfl_xor(s4[g], off, 16);
                    if (sub == 0) {
                        const int pl = p - p0;
                        S[0 * CLEN + pl] = s4[0] * scale;
                        S[1 * CLEN + pl] = s4[1] * scale;
                        S[2 * CLEN + pl] = s4[2] * scale;
                        S[3 * CLEN + pl] = s4[3] * scale;
                    }
                }
            }
        }
    }
    __syncthreads();

    // ---- patch position cur with the NEW k ----
    if (cur >= p0 && cur < pend && t < 4) {
        float a = 0.f;
        for (int d = 0; d < D; ++d) a = fmaf(qs[t * D + d], kn[d], a);
        S[t * CLEN + cur - p0] = a * scale;
    }
    __syncthreads();

    // ---- partial softmax (waves 0..3, one per g) ----
    {
        float m = -1e30f;
        for (int p = l; p < cnt; p += 64) m = fmaxf(m, S[w * CLEN + p]);
#pragma unroll
        for (int off = 32; off; off >>= 1) m = fmaxf(m, __shfl_xor(m, off, 64));
        float sum = 0.f;
        for (int p = l; p < cnt; p += 64) {
            const float e = __expf(S[w * CLEN + p] - m);
            S[w * CLEN + p] = e;
            sum += e;
        }
#pragma unroll
        for (int off = 32; off; off >>= 1) sum += __shfl_xor(sum, off, 64);
        if (l == 0) { sm_m[w] = m; sm_s[w] = sum; }
    }
    __syncthreads();

    // ---- pass 2: PV (unnormalized). thread owns 8 d's, strides p by 16. ----
    {
        const int s = t & 15, pt = t >> 4;      // pt 0..15
        const int d0 = s * 8;
        float acc[4][8];
#pragma unroll
        for (int g = 0; g < 4; ++g)
#pragma unroll
            for (int j = 0; j < 8; ++j) acc[g][j] = 0.f;

        if (full) {
            const float* vp = cache_v + base + (size_t)(p0 + pt) * D + d0;
            float4 A = *(const float4*)vp;
            float4 C = *(const float4*)(vp + 4);
            int pl = pt;
            for (int it = 0; it < CLEN / 16; ++it) {
                const float4 a = A, cc = C;
                vp += step;
                if (it + 1 < CLEN / 16) {
                    A = *(const float4*)vp;
                    C = *(const float4*)(vp + 4);
                }
                const float vv[8] = {a.x, a.y, a.z, a.w, cc.x, cc.y, cc.z, cc.w};
                const float s0 = S[0 * CLEN + pl], s1 = S[1 * CLEN + pl];
                const float s2 = S[2 * CLEN + pl], s3 = S[3 * CLEN + pl];
#pragma unroll
                for (int j = 0; j < 8; ++j) {
                    acc[0][j] = fmaf(s0, vv[j], acc[0][j]);
                    acc[1][j] = fmaf(s1, vv[j], acc[1][j]);
                    acc[2][j] = fmaf(s2, vv[j], acc[2][j]);
                    acc[3][j] = fmaf(s3, vv[j], acc[3][j]);
                }
                pl += 16;
            }
            // post-hoc fix of position cur: acc += S[cur]*(vn - v_cached)
            if (cur >= p0 && cur < pend && pt == ((cur - p0) & 15)) {
                const float* vc = cache_v + base + (size_t)cur * D + d0;
                const float4 a = *(const float4*)vc;
                const float4 cc = *(const float4*)(vc + 4);
                const float vv[8] = {a.x, a.y, a.z, a.w, cc.x, cc.y, cc.z, cc.w};
                const int pl2 = cur - p0;
                const float s0 = S[0 * CLEN + pl2], s1 = S[1 * CLEN + pl2];
                const float s2 = S[2 * CLEN + pl2], s3 = S[3 * CLEN + pl2];
#pragma unroll
                for (int j = 0; j < 8; ++j) {
                    const float dv = vn[d0 + j] - vv[j];
                    acc[0][j] = fmaf(s0, dv, acc[0][j]);
                    acc[1][j] = fmaf(s1, dv, acc[1][j]);
                    acc[2][j] = fmaf(s2, dv, acc[2][j]);
                    acc[3][j] = fmaf(s3, dv, acc[3][j]);
                }
            }
        } else {
            float vn8[8];
#pragma unroll
            for (int j = 0; j < 8; ++j) vn8[j] = vn[d0 + j];
            for (int i = 0; i < CLEN / 16; ++i) {
                const int p = p0 + i * 16 + pt;
                if (p < pend) {
                    const float4 a = *(const float4*)(cache_v + base + (size_t)p * D + d0);
                    const float4 cc = *(const float4*)(cache_v + base + (size_t)p * D + d0 + 4);
                    float vv[8] = {a.x, a.y, a.z, a.w, cc.x, cc.y, cc.z, cc.w};
                    if (p == cur) {
#pragma unroll
                        for (int j = 0; j < 8; ++j) vv[j] = vn8[j];
                    }
                    const int pl = p - p0;
                    const float s0 = S[0 * CLEN + pl], s1 = S[1 * CLEN + pl];
                    const float s2 = S[2 * CLEN + pl], s3 = S[3 * CLEN + pl];
#pragma unroll
                    for (int j = 0; j < 8; ++j) {
                        acc[0][j] = fmaf(s0, vv[j], acc[0][j]);
                        acc[1][j] = fmaf(s1, vv[j], acc[1][j]);
                        acc[2][j] = fmaf(s2, vv[j], acc[2][j]);
                        acc[3][j] = fmaf(s3, vv[j], acc[3][j]);
                    }
                }
            }
        }
        // reduce over the 4 in-wave pt-groups (lane bits 4,5)
#pragma unroll
        for (int off = 16; off <= 32; off <<= 1)
#pragma unroll
            for (int g = 0; g < 4; ++g)
#pragma unroll
                for (int j = 0; j < 8; ++j)
                    acc[g][j] += __shfl_xor(acc[g][j], off, 64);
        if (l < 16) {
#pragma unroll
            for (int g = 0; g < 4; ++g)
#pragma unroll
                for (int j = 0; j < 8; ++j)
                    red[(w * 4 + g) * D + l * 8 + j] = acc[g][j];
        }
    }
    __syncthreads();

    {   // cross-wave reduce + write partials (each thread covers 2 heads)
        const int d = t & 127, half = t >> 7;   // half 0..1
#pragma unroll
        for (int gi = 0; gi < 2; ++gi) {
            const int g = half + gi * 2;
            float sum = 0.f;
#pragma unroll
            for (int w4 = 0; w4 < 4; ++w4) sum += red[(w4 * 4 + g) * D + d];
            const int hidx = bkv * GQ + g;
            pacc[((size_t)hidx * NCHK + c) * D + d] = sum;
            if (d == 0) {
                pm[hidx * NCHK + c]   = sm_m[g];
                psum[hidx * NCHK + c] = sm_s[g];
            }
        }
    }
}

// ------- combine partial chunks: one block per (b, kv), 512 threads -------
__global__ __launch_bounds__(512) void k_attn_combine(
        const float* __restrict__ pacc, const float* __restrict__ pm,
        const float* __restrict__ psum, float* __restrict__ attn_out) {
    const int t = threadIdx.x;
    const int bkv = blockIdx.x;
    const int b = bkv >> 3, kv = bkv & 7;
    const int g = t >> 7, d = t & 127;
    const int hidx = bkv * GQ + g;

    float mm[NCHK];
    float m = -1e30f;
#pragma unroll
    for (int c = 0; c < NCHK; ++c) {
        mm[c] = pm[hidx * NCHK + c];
        m = fmaxf(m, mm[c]);
    }
    float tot = 0.f, acc = 0.f;
#pragma unroll
    for (int c = 0; c < NCHK; ++c) {
        const float wgt = __expf(mm[c] - m);
        tot = fmaf(psum[hidx * NCHK + c], wgt, tot);
        acc = fmaf(pacc[((size_t)hidx * NCHK + c) * D + d], wgt, acc);
    }
    attn_out[(size_t)b * HID + (kv * GQ + g) * D + d] = acc / tot;
}

// ---------------- host launch ----------------
extern "C" void kernel_launch(void* const* d_in, const int* in_sizes, int n_in,
                              void* d_out, int out_size, void* d_ws, size_t ws_size,
                              hipStream_t stream) {
    const float* x    = (const float*)d_in[0];
    const float* wqkv = (const float*)d_in[1];
    const float* wo   = (const float*)d_in[2];
    const float* rot  = (const float*)d_in[3];
    const float* ck   = (const float*)d_in[4];
    const float* cv   = (const float*)d_in[5];
    const int*   sp   = (const int*)d_in[6];
    const int*   cp   = (const int*)d_in[7];

    float* ws     = (float*)d_ws;
    float* xqkv_o = ws;                     // 32*6144   = 196608
    float* q_rot  = ws + 196608;            // 32*32*128 = 131072
    float* k_rot  = ws + 327680;            // 32*8*128  = 32768
    float* attn_o = ws + 360448;            // 32*4096   = 131072
    float* part   = ws + 491520;            // NCH*32*6144 = 3145728 (GEMM partials)
    // attention partials alias the part region (disjoint in time):
    float* pacc   = part;                   // 1024*8*128 = 1048576
    float* pm     = part + 1048576;         // 8192
    float* psum   = part + 1056768;         // 8192

    k_gemm_split<EQKV><<<dim3(EQKV / 128, NCH), 256, 0, stream>>>(x, wqkv, part);
    k_reduce_f32<<<192, 256, 0, stream>>>(part, xqkv_o, 32 * EQKV);
    k_rope<<<32 * (NH + NKV), 128, 0, stream>>>(xqkv_o, rot, q_rot, k_rot);
    k_attn_part<<<256 * NCHK, 256, 0, stream>>>(q_rot, k_rot, xqkv_o, ck, cv,
                                                sp, cp, pacc, pm, psum);
    k_attn_combine<<<256, 512, 0, stream>>>(pacc, pm, psum, attn_o);
    k_gemm_split<HID><<<dim3(HID / 128, NCH), 256, 0, stream>>>(attn_o, wo, part);
    k_reduce_f32<<<128, 256, 0, stream>>>(part, (float*)d_out, 32 * HID);
}

// Round 9
// 174.246 us; speedup vs baseline: 4.1411x; 1.0095x over previous
//
#include <hip/hip_runtime.h>
#include <hip/hip_bf16.h>

#define HID 4096
#define EQKV 6144
#define NH 32
#define NKV 8
#define GQ 4
#define D 128
#define WIN 2048
#define NCH 16   // K-chunks for split-K GEMM (4096 / 256)
#define NCHK 8   // position chunks for flash-decode attention
#define CLEN (WIN / NCHK)   // 256

// ------- split-K GEMM: part[chunk][b][e] = sum_{h in chunk} X[b][h] * W[h][e]
template<int E>
__global__ __launch_bounds__(256) void k_gemm_split(const float* __restrict__ X,
                                                    const float* __restrict__ W,
                                                    float* __restrict__ part) {
    __shared__ float xs[256][36];
    __shared__ float2 red[8][64][4];
    const int t = threadIdx.x;
    const int wv = t >> 6, ln = t & 63;
    const int e = blockIdx.x * 128 + ln * 2;
    const int h0 = blockIdx.y * 256;

    {   // stage X[0..32)[h0..h0+256) -> xs[hl][b]
        const int bs = t >> 3, hs = (t & 7) * 32;
#pragma unroll
        for (int i = 0; i < 8; ++i) {
            const float4 v = *(const float4*)&X[(size_t)bs * HID + h0 + hs + i * 4];
            xs[hs + i * 4 + 0][bs] = v.x;
            xs[hs + i * 4 + 1][bs] = v.y;
            xs[hs + i * 4 + 2][bs] = v.z;
            xs[hs + i * 4 + 3][bs] = v.w;
        }
    }
    __syncthreads();

    float2 acc[32];
#pragma unroll
    for (int i = 0; i < 32; ++i) acc[i] = make_float2(0.f, 0.f);

    const float* Wp = W + (size_t)(h0 + wv * 64) * E + e;
    const int hl0 = wv * 64;
    float2 wb[4];
#pragma unroll
    for (int i = 0; i < 4; ++i) wb[i] = *(const float2*)(Wp + (size_t)i * E);
    Wp += (size_t)4 * E;

    for (int hh = 0; hh < 64; hh += 4) {
        float2 wc[4];
#pragma unroll
        for (int i = 0; i < 4; ++i) wc[i] = wb[i];
        if (hh + 4 < 64) {
#pragma unroll
            for (int i = 0; i < 4; ++i) wb[i] = *(const float2*)(Wp + (size_t)i * E);
            Wp += (size_t)4 * E;
        }
#pragma unroll
        for (int i = 0; i < 4; ++i) {
            const float wx = wc[i].x, wy = wc[i].y;
            const int row = hl0 + hh + i;
#pragma unroll
            for (int q = 0; q < 8; ++q) {
                const float4 xv = *(const float4*)&xs[row][q * 4];
                acc[q * 4 + 0].x = fmaf(xv.x, wx, acc[q * 4 + 0].x);
                acc[q * 4 + 0].y = fmaf(xv.x, wy, acc[q * 4 + 0].y);
                acc[q * 4 + 1].x = fmaf(xv.y, wx, acc[q * 4 + 1].x);
                acc[q * 4 + 1].y = fmaf(xv.y, wy, acc[q * 4 + 1].y);
                acc[q * 4 + 2].x = fmaf(xv.z, wx, acc[q * 4 + 2].x);
                acc[q * 4 + 2].y = fmaf(xv.z, wy, acc[q * 4 + 2].y);
                acc[q * 4 + 3].x = fmaf(xv.w, wx, acc[q * 4 + 3].x);
                acc[q * 4 + 3].y = fmaf(xv.w, wy, acc[q * 4 + 3].y);
            }
        }
    }

    for (int r = 0; r < 4; ++r) {
#pragma unroll
        for (int j = 0; j < 8; ++j) red[j][ln][wv] = acc[r * 8 + j];
        __syncthreads();
#pragma unroll
        for (int it = 0; it < 2; ++it) {
            const int item = t + it * 256;
            const int ln2 = item & 63, j2 = item >> 6;
            const float2 a0 = red[j2][ln2][0], a1 = red[j2][ln2][1];
            const float2 a2 = red[j2][ln2][2], a3 = red[j2][ln2][3];
            const float2 s = make_float2((a0.x + a1.x) + (a2.x + a3.x),
                                         (a0.y + a1.y) + (a2.y + a3.y));
            const int b2 = r * 8 + j2;
            const int e2 = blockIdx.x * 128 + ln2 * 2;
            *(float2*)(part + ((size_t)blockIdx.y * 32 + b2) * E + e2) = s;
        }
        __syncthreads();
    }
}

// ---------------- final reduce of wo-GEMM partials -> d_out ----------------
__global__ void k_reduce_f32(const float* __restrict__ part,
                             float* __restrict__ out, const int n) {
    const int i4 = (blockIdx.x * 256 + threadIdx.x) * 4;
    if (i4 >= n) return;
    float4 s = make_float4(0.f, 0.f, 0.f, 0.f);
#pragma unroll
    for (int c = 0; c < NCH; ++c) {
        const float4 p = *(const float4*)(part + (size_t)c * n + i4);
        s.x += p.x; s.y += p.y; s.z += p.z; s.w += p.w;
    }
    *(float4*)(out + i4) = s;
}

// ------- fused: reduce qkv partials + rope (q,k) + v extract -------
// grid: 32 b x 48 units (32 q heads, 8 k, 8 v), 128 threads.
__global__ __launch_bounds__(128) void k_finish(
        const float* __restrict__ part, const float* __restrict__ R,
        float* __restrict__ q_rot, float* __restrict__ k_rot,
        float* __restrict__ v_new) {
    __shared__ float sq[D];
    const int bid = blockIdx.x;
    const int b = bid / 48, u = bid % 48;
    const int tid = threadIdx.x;
    const int e0 = u * D;

    float s = 0.f;
#pragma unroll
    for (int c = 0; c < NCH; ++c)
        s += part[((size_t)c * 32 + b) * EQKV + e0 + tid];

    if (u < 40) {   // q or k: rope
        sq[tid] = s;
        __syncthreads();
        float acc = 0.f;
        for (int d = 0; d < D; d += 4) {
            const float r0 = R[(size_t)(d + 0) * D + tid];
            const float r1 = R[(size_t)(d + 1) * D + tid];
            const float r2 = R[(size_t)(d + 2) * D + tid];
            const float r3 = R[(size_t)(d + 3) * D + tid];
            acc = fmaf(sq[d + 0], r0, acc);
            acc = fmaf(sq[d + 1], r1, acc);
            acc = fmaf(sq[d + 2], r2, acc);
            acc = fmaf(sq[d + 3], r3, acc);
        }
        if (u < 32) q_rot[((size_t)b * NH + u) * D + tid] = acc;
        else        k_rot[((size_t)b * NKV + (u - 32)) * D + tid] = acc;
    } else {        // v: plain reduce
        v_new[((size_t)b * NKV + (u - 40)) * D + tid] = s;
    }
}

// ------- flash-decode attention partial: one block per (b, kv, chunk) -------
__global__ __launch_bounds__(256) void k_attn_part(
        const float* __restrict__ q_rot, const float* __restrict__ k_rot,
        const float* __restrict__ v_new,
        const float* __restrict__ cache_k, const float* __restrict__ cache_v,
        const int* __restrict__ p_start, const int* __restrict__ p_cur,
        float* __restrict__ pacc, float* __restrict__ pm, float* __restrict__ psum) {
    __shared__ float qs[4 * D];
    __shared__ float kn[D];
    __shared__ float vn[D];
    __shared__ float S[4 * CLEN];
    __shared__ float sm_m[4], sm_s[4];
    __shared__ float red[4 * 4 * D];

    const int t = threadIdx.x;
    const int bid = blockIdx.x;
    const int bkv = bid >> 3, c = bid & (NCHK - 1);
    const int b = bkv >> 3, kv = bkv & 7;
    const int l = t & 63, w = t >> 6;       // w in 0..3
    const int ls = min(p_start[0] + 1, WIN);
    const int cur = p_cur[0];
    const int p0 = c * CLEN;
    const int pend = min(ls, p0 + CLEN);
    const int cnt = pend - p0;
    const bool full = (cnt == CLEN);

    {   // stage q (4 heads), new k, new v
        const float* qsrc = q_rot + ((size_t)b * NH + kv * GQ) * D;
        qs[t] = qsrc[t];
        qs[t + 256] = qsrc[t + 256];
        if (t < 128) kn[t] = k_rot[((size_t)b * NKV + kv) * D + t];
        else vn[t - 128] = v_new[((size_t)b * NKV + kv) * D + (t - 128)];
    }
    __syncthreads();

    const float scale = 0.08838834764831845f;   // 1/sqrt(128)
    const size_t base = (size_t)bkv * WIN * D;

    // ---- pass 1: scores. 8 lanes per row (lane owns 16 d's); 32 rows/iter. ----
    {
        const int sub = l & 7, r = l >> 3;
        const int d0 = sub * 16;
        const int row0 = w * 8 + r;             // 0..31
        float qreg[4][16];
#pragma unroll
        for (int g = 0; g < 4; ++g)
#pragma unroll
            for (int j = 0; j < 16; ++j) qreg[g][j] = qs[g * D + d0 + j] * scale;

        if (full) {
            const float* kp = cache_k + base + (size_t)(p0 + row0) * D + d0;
            float4 A0 = *(const float4*)kp;
            float4 A1 = *(const float4*)(kp + 4);
            float4 A2 = *(const float4*)(kp + 8);
            float4 A3 = *(const float4*)(kp + 12);
            int pl = row0;
            for (int it = 0; it < CLEN / 32; ++it) {
                const float4 a0 = A0, a1 = A1, a2 = A2, a3 = A3;
                kp += (size_t)32 * D;
                if (it + 1 < CLEN / 32) {
                    A0 = *(const float4*)kp;
                    A1 = *(const float4*)(kp + 4);
                    A2 = *(const float4*)(kp + 8);
                    A3 = *(const float4*)(kp + 12);
                }
                const float kk[16] = {a0.x, a0.y, a0.z, a0.w, a1.x, a1.y, a1.z, a1.w,
                                      a2.x, a2.y, a2.z, a2.w, a3.x, a3.y, a3.z, a3.w};
                float s4[4] = {0.f, 0.f, 0.f, 0.f};
#pragma unroll
                for (int g = 0; g < 4; ++g)
#pragma unroll
                    for (int j = 0; j < 16; ++j) s4[g] = fmaf(qreg[g][j], kk[j], s4[g]);
#pragma unroll
                for (int off = 1; off < 8; off <<= 1)
#pragma unroll
                    for (int g = 0; g < 4; ++g) s4[g] += __shfl_xor(s4[g], off, 8);
                if (sub == 0) {
                    S[0 * CLEN + pl] = s4[0];
                    S[1 * CLEN + pl] = s4[1];
                    S[2 * CLEN + pl] = s4[2];
                    S[3 * CLEN + pl] = s4[3];
                }
                pl += 32;
            }
        } else {
            for (int it = 0; it < CLEN / 32; ++it) {
                const int p = p0 + it * 32 + row0;
                if (p < pend) {
                    const float* kp = cache_k + base + (size_t)p * D + d0;
                    const float4 a0 = *(const float4*)kp;
                    const float4 a1 = *(const float4*)(kp + 4);
                    const float4 a2 = *(const float4*)(kp + 8);
                    const float4 a3 = *(const float4*)(kp + 12);
                    const float kk[16] = {a0.x, a0.y, a0.z, a0.w, a1.x, a1.y, a1.z, a1.w,
                                          a2.x, a2.y, a2.z, a2.w, a3.x, a3.y, a3.z, a3.w};
                    float s4[4] = {0.f, 0.f, 0.f, 0.f};
#pragma unroll
                    for (int g = 0; g < 4; ++g)
#pragma unroll
                        for (int j = 0; j < 16; ++j) s4[g] = fmaf(qreg[g][j], kk[j], s4[g]);
#pragma unroll
                    for (int off = 1; off < 8; off <<= 1)
#pragma unroll
                        for (int g = 0; g < 4; ++g) s4[g] += __shfl_xor(s4[g], off, 8);
                    if (sub == 0) {
                        const int pl = p - p0;
                        S[0 * CLEN + pl] = s4[0];
                        S[1 * CLEN + pl] = s4[1];
                        S[2 * CLEN + pl] = s4[2];
                        S[3 * CLEN + pl] = s4[3];
                    }
                }
            }
        }
    }
    __syncthreads();

    // ---- patch position cur with the NEW k ----
    if (cur >= p0 && cur < pend && t < 4) {
        float a = 0.f;
        for (int d = 0; d < D; ++d) a = fmaf(qs[t * D + d], kn[d], a);
        S[t * CLEN + cur - p0] = a * scale;
    }
    __syncthreads();

    // ---- partial softmax (waves 0..3, one per g) ----
    {
        float m = -1e30f;
        for (int p = l; p < cnt; p += 64) m = fmaxf(m, S[w * CLEN + p]);
#pragma unroll
        for (int off = 32; off; off >>= 1) m = fmaxf(m, __shfl_xor(m, off, 64));
        float sum = 0.f;
        for (int p = l; p < cnt; p += 64) {
            const float e = __expf(S[w * CLEN + p] - m);
            S[w * CLEN + p] = e;
            sum += e;
        }
#pragma unroll
        for (int off = 32; off; off >>= 1) sum += __shfl_xor(sum, off, 64);
        if (l == 0) { sm_m[w] = m; sm_s[w] = sum; }
    }
    __syncthreads();

    // ---- pass 2: PV (unnormalized). thread owns 8 d's, strides p by 16. ----
    {
        const int s = t & 15, pt = t >> 4;      // pt 0..15
        const int d0 = s * 8;
        float acc[4][8];
#pragma unroll
        for (int g = 0; g < 4; ++g)
#pragma unroll
            for (int j = 0; j < 8; ++j) acc[g][j] = 0.f;

        if (full) {
            const float* vp = cache_v + base + (size_t)(p0 + pt) * D + d0;
            float4 A = *(const float4*)vp;
            float4 C = *(const float4*)(vp + 4);
            int pl = pt;
            for (int it = 0; it < CLEN / 16; ++it) {
                const float4 a = A, cc = C;
                vp += (size_t)16 * D;
                if (it + 1 < CLEN / 16) {
                    A = *(const float4*)vp;
                    C = *(const float4*)(vp + 4);
                }
                const float vv[8] = {a.x, a.y, a.z, a.w, cc.x, cc.y, cc.z, cc.w};
                const float s0 = S[0 * CLEN + pl], s1 = S[1 * CLEN + pl];
                const float s2 = S[2 * CLEN + pl], s3 = S[3 * CLEN + pl];
#pragma unroll
                for (int j = 0; j < 8; ++j) {
                    acc[0][j] = fmaf(s0, vv[j], acc[0][j]);
                    acc[1][j] = fmaf(s1, vv[j], acc[1][j]);
                    acc[2][j] = fmaf(s2, vv[j], acc[2][j]);
                    acc[3][j] = fmaf(s3, vv[j], acc[3][j]);
                }
                pl += 16;
            }
            // post-hoc fix of position cur: acc += S[cur]*(vn - v_cached)
            if (cur >= p0 && cur < pend && pt == ((cur - p0) & 15)) {
                const float* vc = cache_v + base + (size_t)cur * D + d0;
                const float4 a = *(const float4*)vc;
                const float4 cc = *(const float4*)(vc + 4);
                const float vv[8] = {a.x, a.y, a.z, a.w, cc.x, cc.y, cc.z, cc.w};
                const int pl2 = cur - p0;
                const float s0 = S[0 * CLEN + pl2], s1 = S[1 * CLEN + pl2];
                const float s2 = S[2 * CLEN + pl2], s3 = S[3 * CLEN + pl2];
#pragma unroll
                for (int j = 0; j < 8; ++j) {
                    const float dv = vn[d0 + j] - vv[j];
                    acc[0][j] = fmaf(s0, dv, acc[0][j]);
                    acc[1][j] = fmaf(s1, dv, acc[1][j]);
                    acc[2][j] = fmaf(s2, dv, acc[2][j]);
                    acc[3][j] = fmaf(s3, dv, acc[3][j]);
                }
            }
        } else {
            float vn8[8];
#pragma unroll
            for (int j = 0; j < 8; ++j) vn8[j] = vn[d0 + j];
            for (int i = 0; i < CLEN / 16; ++i) {
                const int p = p0 + i * 16 + pt;
                if (p < pend) {
                    const float4 a = *(const float4*)(cache_v + base + (size_t)p * D + d0);
                    const float4 cc = *(const float4*)(cache_v + base + (size_t)p * D + d0 + 4);
                    float vv[8] = {a.x, a.y, a.z, a.w, cc.x, cc.y, cc.z, cc.w};
                    if (p == cur) {
#pragma unroll
                        for (int j = 0; j < 8; ++j) vv[j] = vn8[j];
                    }
                    const int pl = p - p0;
                    const float s0 = S[0 * CLEN + pl], s1 = S[1 * CLEN + pl];
                    const float s2 = S[2 * CLEN + pl], s3 = S[3 * CLEN + pl];
#pragma unroll
                    for (int j = 0; j < 8; ++j) {
                        acc[0][j] = fmaf(s0, vv[j], acc[0][j]);
                        acc[1][j] = fmaf(s1, vv[j], acc[1][j]);
                        acc[2][j] = fmaf(s2, vv[j], acc[2][j]);
                        acc[3][j] = fmaf(s3, vv[j], acc[3][j]);
                    }
                }
            }
        }
        // reduce over the 4 in-wave pt-groups (lane bits 4,5)
#pragma unroll
        for (int off = 16; off <= 32; off <<= 1)
#pragma unroll
            for (int g = 0; g < 4; ++g)
#pragma unroll
                for (int j = 0; j < 8; ++j)
                    acc[g][j] += __shfl_xor(acc[g][j], off, 64);
        if (l < 16) {
#pragma unroll
            for (int g = 0; g < 4; ++g)
#pragma unroll
                for (int j = 0; j < 8; ++j)
                    red[(w * 4 + g) * D + l * 8 + j] = acc[g][j];
        }
    }
    __syncthreads();

    {   // cross-wave reduce + write partials (each thread covers 2 heads)
        const int d = t & 127, half = t >> 7;
#pragma unroll
        for (int gi = 0; gi < 2; ++gi) {
            const int g = half + gi * 2;
            float sum = 0.f;
#pragma unroll
            for (int w4 = 0; w4 < 4; ++w4) sum += red[(w4 * 4 + g) * D + d];
            const int hidx = bkv * GQ + g;
            pacc[((size_t)hidx * NCHK + c) * D + d] = sum;
            if (d == 0) {
                pm[hidx * NCHK + c]   = sm_m[g];
                psum[hidx * NCHK + c] = sm_s[g];
            }
        }
    }
}

// ------- combine partial chunks: one block per (b, kv), 512 threads -------
__global__ __launch_bounds__(512) void k_attn_combine(
        const float* __restrict__ pacc, const float* __restrict__ pm,
        const float* __restrict__ psum, float* __restrict__ attn_out) {
    const int t = threadIdx.x;
    const int bkv = blockIdx.x;
    const int b = bkv >> 3, kv = bkv & 7;
    const int g = t >> 7, d = t & 127;
    const int hidx = bkv * GQ + g;

    float mm[NCHK];
    float m = -1e30f;
#pragma unroll
    for (int c = 0; c < NCHK; ++c) {
        mm[c] = pm[hidx * NCHK + c];
        m = fmaxf(m, mm[c]);
    }
    float tot = 0.f, acc = 0.f;
#pragma unroll
    for (int c = 0; c < NCHK; ++c) {
        const float wgt = __expf(mm[c] - m);
        tot = fmaf(psum[hidx * NCHK + c], wgt, tot);
        acc = fmaf(pacc[((size_t)hidx * NCHK + c) * D + d], wgt, acc);
    }
    attn_out[(size_t)b * HID + (kv * GQ + g) * D + d] = acc / tot;
}

// ---------------- host launch ----------------
extern "C" void kernel_launch(void* const* d_in, const int* in_sizes, int n_in,
                              void* d_out, int out_size, void* d_ws, size_t ws_size,
                              hipStream_t stream) {
    const float* x    = (const float*)d_in[0];
    const float* wqkv = (const float*)d_in[1];
    const float* wo   = (const float*)d_in[2];
    const float* rot  = (const float*)d_in[3];
    const float* ck   = (const float*)d_in[4];
    const float* cv   = (const float*)d_in[5];
    const int*   sp   = (const int*)d_in[6];
    const int*   cp   = (const int*)d_in[7];

    float* ws     = (float*)d_ws;
    float* q_rot  = ws;                     // 32*32*128 = 131072
    float* k_rot  = ws + 131072;            // 32*8*128  = 32768
    float* v_new  = ws + 163840;            // 32*8*128  = 32768
    float* attn_o = ws + 196608;            // 32*4096   = 131072
    float* part   = ws + 327680;            // NCH*32*6144 = 3145728 (GEMM partials)
    // attention partials alias the part region (disjoint in time):
    float* pacc   = part;                   // 1024*8*128 = 1048576
    float* pm     = part + 1048576;         // 8192
    float* psum   = part + 1056768;         // 8192

    k_gemm_split<EQKV><<<dim3(EQKV / 128, NCH), 256, 0, stream>>>(x, wqkv, part);
    k_finish<<<32 * 48, 128, 0, stream>>>(part, rot, q_rot, k_rot, v_new);
    k_attn_part<<<256 * NCHK, 256, 0, stream>>>(q_rot, k_rot, v_new, ck, cv,
                                                sp, cp, pacc, pm, psum);
    k_attn_combine<<<256, 512, 0, stream>>>(pacc, pm, psum, attn_o);
    k_gemm_split<HID><<<dim3(HID / 128, NCH), 256, 0, stream>>>(attn_o, wo, part);
    k_reduce_f32<<<128, 256, 0, stream>>>(part, (float*)d_out, 32 * HID);
}